// Round 1
// baseline (4022.702 us; speedup 1.0000x reference)
//
#include <hip/hip_runtime.h>
#include <cmath>

#define B_DIM 4096
#define O_DIM 2048
#define I_DIM 2048

#define BM 64
#define BN 64
#define BK 16
#define TM 4
#define TN 4
// block = 16x16 = 256 threads; each thread computes a strided 4x4 micro-tile.

template <typename LT> struct vec4t;
template <> struct vec4t<float>  { using T = float4; };
template <> struct vec4t<double> { using T = double4; };

// ---------------------------------------------------------------------------
// Kernel A: L1[b,o] = sum_i x[b,i] * Wsyn[o,i] + bsyn[o]   (NT GEMM, f64 acc)
// ---------------------------------------------------------------------------
template <typename LT>
__global__ __launch_bounds__(256)
void lsnn_l1_kernel(const float* __restrict__ X,
                    const float* __restrict__ Wsyn,
                    const float* __restrict__ bsyn,
                    LT* __restrict__ L1) {
    __shared__ double As[BM][BK + 1];
    __shared__ double Bs[BN][BK + 1];

    const int tid = threadIdx.x;
    const int tx = tid & 15;
    const int ty = tid >> 4;
    const int row0 = blockIdx.y * BM;   // over B
    const int col0 = blockIdx.x * BN;   // over O

    double acc[TM][TN];
#pragma unroll
    for (int i = 0; i < TM; i++)
#pragma unroll
        for (int j = 0; j < TN; j++) acc[i][j] = 0.0;

    const int lin = tid * 4;
    const int lr = lin >> 4;   // 0..63
    const int lc = lin & 15;   // 0,4,8,12

    for (int k0 = 0; k0 < I_DIM; k0 += BK) {
        const float4 av = *(const float4*)(X    + (size_t)(row0 + lr) * I_DIM + k0 + lc);
        const float4 bv = *(const float4*)(Wsyn + (size_t)(col0 + lr) * I_DIM + k0 + lc);
        As[lr][lc + 0] = av.x; As[lr][lc + 1] = av.y;
        As[lr][lc + 2] = av.z; As[lr][lc + 3] = av.w;
        Bs[lr][lc + 0] = bv.x; Bs[lr][lc + 1] = bv.y;
        Bs[lr][lc + 2] = bv.z; Bs[lr][lc + 3] = bv.w;
        __syncthreads();
#pragma unroll
        for (int kk = 0; kk < BK; kk++) {
            double a[TM], b[TN];
#pragma unroll
            for (int i = 0; i < TM; i++) a[i] = As[ty + 16 * i][kk];
#pragma unroll
            for (int j = 0; j < TN; j++) b[j] = Bs[tx + 16 * j][kk];
#pragma unroll
            for (int i = 0; i < TM; i++)
#pragma unroll
                for (int j = 0; j < TN; j++)
                    acc[i][j] = fma(a[i], b[j], acc[i][j]);
        }
        __syncthreads();
    }

#pragma unroll
    for (int i = 0; i < TM; i++) {
        const int r = row0 + ty + 16 * i;
#pragma unroll
        for (int j = 0; j < TN; j++) {
            const int c = col0 + tx + 16 * j;
            L1[(size_t)r * O_DIM + c] = (LT)(acc[i][j] + (double)bsyn[c]);
        }
    }
}

// ---------------------------------------------------------------------------
// Kernel B: dual GEMM
//   zm[b,o] = sum_k (L1[b,k]+u_t[b,k]) * WTm[o,k]  + bTm[o]
//   za[b,o] = sum_k (L1[b,k]+b_t[b,k]) * WTa[o,k]  + bTa[o]
// epilogue: alpha/rho sigmoids, thr, u_new, spike.
// ---------------------------------------------------------------------------
template <typename LT>
__global__ __launch_bounds__(256)
void lsnn_stage2_kernel(const LT* __restrict__ L1,
                        const float* __restrict__ u_t,
                        const float* __restrict__ b_t,
                        const float* __restrict__ spk,
                        const float* __restrict__ WTm,
                        const float* __restrict__ bTm,
                        const float* __restrict__ WTa,
                        const float* __restrict__ bTa,
                        float* __restrict__ out) {
    __shared__ double A1s[BM][BK + 1];
    __shared__ double A2s[BM][BK + 1];
    __shared__ double Bms[BN][BK + 1];
    __shared__ double Bas[BN][BK + 1];

    const int tid = threadIdx.x;
    const int tx = tid & 15;
    const int ty = tid >> 4;
    const int row0 = blockIdx.y * BM;   // over B
    const int col0 = blockIdx.x * BN;   // over O

    double accM[TM][TN], accA[TM][TN];
#pragma unroll
    for (int i = 0; i < TM; i++)
#pragma unroll
        for (int j = 0; j < TN; j++) { accM[i][j] = 0.0; accA[i][j] = 0.0; }

    const int lin = tid * 4;
    const int lr = lin >> 4;   // 0..63
    const int lc = lin & 15;   // 0,4,8,12

    using LV4 = typename vec4t<LT>::T;

    for (int k0 = 0; k0 < O_DIM; k0 += BK) {
        const size_t arow = (size_t)(row0 + lr) * O_DIM + k0 + lc;
        const LV4 lv = *(const LV4*)(L1 + arow);
        const float4 uv = *(const float4*)(u_t + arow);
        const float4 bv = *(const float4*)(b_t + arow);
        A1s[lr][lc + 0] = (double)lv.x + (double)uv.x;
        A1s[lr][lc + 1] = (double)lv.y + (double)uv.y;
        A1s[lr][lc + 2] = (double)lv.z + (double)uv.z;
        A1s[lr][lc + 3] = (double)lv.w + (double)uv.w;
        A2s[lr][lc + 0] = (double)lv.x + (double)bv.x;
        A2s[lr][lc + 1] = (double)lv.y + (double)bv.y;
        A2s[lr][lc + 2] = (double)lv.z + (double)bv.z;
        A2s[lr][lc + 3] = (double)lv.w + (double)bv.w;

        const size_t brow = (size_t)(col0 + lr) * O_DIM + k0 + lc;
        const float4 wm = *(const float4*)(WTm + brow);
        const float4 wa = *(const float4*)(WTa + brow);
        Bms[lr][lc + 0] = wm.x; Bms[lr][lc + 1] = wm.y;
        Bms[lr][lc + 2] = wm.z; Bms[lr][lc + 3] = wm.w;
        Bas[lr][lc + 0] = wa.x; Bas[lr][lc + 1] = wa.y;
        Bas[lr][lc + 2] = wa.z; Bas[lr][lc + 3] = wa.w;
        __syncthreads();
#pragma unroll
        for (int kk = 0; kk < BK; kk++) {
            double a1[TM], a2[TM], bm[TN], ba[TN];
#pragma unroll
            for (int i = 0; i < TM; i++) {
                a1[i] = A1s[ty + 16 * i][kk];
                a2[i] = A2s[ty + 16 * i][kk];
            }
#pragma unroll
            for (int j = 0; j < TN; j++) {
                bm[j] = Bms[tx + 16 * j][kk];
                ba[j] = Bas[tx + 16 * j][kk];
            }
#pragma unroll
            for (int i = 0; i < TM; i++)
#pragma unroll
                for (int j = 0; j < TN; j++) {
                    accM[i][j] = fma(a1[i], bm[j], accM[i][j]);
                    accA[i][j] = fma(a2[i], ba[j], accA[i][j]);
                }
        }
        __syncthreads();
    }

#pragma unroll
    for (int i = 0; i < TM; i++) {
        const int r = row0 + ty + 16 * i;
#pragma unroll
        for (int j = 0; j < TN; j++) {
            const int c = col0 + tx + 16 * j;
            const size_t idx = (size_t)r * O_DIM + c;

            const double zm = accM[i][j] + (double)bTm[c];
            const double za = accA[i][j] + (double)bTa[c];
            const double alpha = 1.0 / (1.0 + exp(-zm));
            const double rho   = 1.0 / (1.0 + exp(-za));

            const double btv = (double)b_t[idx];
            const double spv = (double)spk[idx];
            const double utv = (double)u_t[idx];
            const double l1v = (double)L1[idx];

            const double b_new = rho * btv + (1.0 - rho) * spv;
            const double thr   = 0.01 + 1.8 * b_new;
            const double u_new = utv + (l1v - utv) / alpha;

            out[idx] = (u_new - thr > 0.0) ? 1.0f : 0.0f;
        }
    }
}

// ---------------------------------------------------------------------------
extern "C" void kernel_launch(void* const* d_in, const int* in_sizes, int n_in,
                              void* d_out, int out_size, void* d_ws, size_t ws_size,
                              hipStream_t stream) {
    const float* x    = (const float*)d_in[0];
    const float* u_t  = (const float*)d_in[1];
    const float* b_t  = (const float*)d_in[2];
    const float* spk  = (const float*)d_in[3];
    const float* Wsyn = (const float*)d_in[4];
    const float* bsyn = (const float*)d_in[5];
    const float* WTm  = (const float*)d_in[6];
    const float* bTm  = (const float*)d_in[7];
    const float* WTa  = (const float*)d_in[8];
    const float* bTa  = (const float*)d_in[9];
    float* out = (float*)d_out;

    dim3 block(256);
    dim3 grid(O_DIM / BN, B_DIM / BM);   // (32, 64)

    const size_t need_d = (size_t)B_DIM * O_DIM * sizeof(double);
    if (ws_size >= need_d) {
        double* L1 = (double*)d_ws;
        lsnn_l1_kernel<double><<<grid, block, 0, stream>>>(x, Wsyn, bsyn, L1);
        lsnn_stage2_kernel<double><<<grid, block, 0, stream>>>(
            L1, u_t, b_t, spk, WTm, bTm, WTa, bTa, out);
    } else {
        float* L1 = (float*)d_ws;
        lsnn_l1_kernel<float><<<grid, block, 0, stream>>>(x, Wsyn, bsyn, L1);
        lsnn_stage2_kernel<float><<<grid, block, 0, stream>>>(
            L1, u_t, b_t, spk, WTm, bTm, WTa, bTa, out);
    }
}

// Round 2
// 1407.406 us; speedup vs baseline: 2.8582x; 2.8582x over previous
//
#include <hip/hip_runtime.h>
#include <cmath>

#define B_DIM 4096
#define O_DIM 2048
#define I_DIM 2048

// fp32 path tiling
#define BM 128
#define BN 128
#define BK 16
#define TM 8
#define TN 8
#define DELTA 1e-3f

// ws layout for fp32 path
#define L1_BYTES ((size_t)B_DIM * O_DIM * sizeof(float))
#define CNT_OFF  L1_BYTES
#define LIST_OFF (L1_BYTES + 256)

// ===========================================================================
// fp32 fast path
// ===========================================================================

// Stage 1: L1[b,o] = x[b,:] . Wsyn[o,:] + bsyn[o]   (fp32)
__global__ __launch_bounds__(256, 2)
void lsnn_l1_f32(const float* __restrict__ X, const float* __restrict__ Wsyn,
                 const float* __restrict__ bsyn, float* __restrict__ L1) {
    __shared__ float As[BK][BM + 4];
    __shared__ float Bs[BK][BN + 4];

    const int tid = threadIdx.x;
    const int tx = tid & 15, ty = tid >> 4;
    const int row0 = blockIdx.y * BM, col0 = blockIdx.x * BN;
    const int ar = tid >> 2, ac = (tid & 3) << 2;

    float acc[TM][TN];
#pragma unroll
    for (int i = 0; i < TM; i++)
#pragma unroll
        for (int j = 0; j < TN; j++) acc[i][j] = 0.0f;

    for (int k0 = 0; k0 < I_DIM; k0 += BK) {
        const float4 a0 = *(const float4*)(X + (size_t)(row0 + ar) * I_DIM + k0 + ac);
        const float4 a1 = *(const float4*)(X + (size_t)(row0 + ar + 64) * I_DIM + k0 + ac);
        const float4 b0 = *(const float4*)(Wsyn + (size_t)(col0 + ar) * I_DIM + k0 + ac);
        const float4 b1 = *(const float4*)(Wsyn + (size_t)(col0 + ar + 64) * I_DIM + k0 + ac);
        As[ac + 0][ar] = a0.x; As[ac + 1][ar] = a0.y; As[ac + 2][ar] = a0.z; As[ac + 3][ar] = a0.w;
        As[ac + 0][ar + 64] = a1.x; As[ac + 1][ar + 64] = a1.y; As[ac + 2][ar + 64] = a1.z; As[ac + 3][ar + 64] = a1.w;
        Bs[ac + 0][ar] = b0.x; Bs[ac + 1][ar] = b0.y; Bs[ac + 2][ar] = b0.z; Bs[ac + 3][ar] = b0.w;
        Bs[ac + 0][ar + 64] = b1.x; Bs[ac + 1][ar + 64] = b1.y; Bs[ac + 2][ar + 64] = b1.z; Bs[ac + 3][ar + 64] = b1.w;
        __syncthreads();
#pragma unroll 4
        for (int kk = 0; kk < BK; kk++) {
            const float4 alo = *(const float4*)&As[kk][ty * 4];
            const float4 ahi = *(const float4*)&As[kk][ty * 4 + 64];
            const float4 blo = *(const float4*)&Bs[kk][tx * 4];
            const float4 bhi = *(const float4*)&Bs[kk][tx * 4 + 64];
            const float a[8] = {alo.x, alo.y, alo.z, alo.w, ahi.x, ahi.y, ahi.z, ahi.w};
            const float b[8] = {blo.x, blo.y, blo.z, blo.w, bhi.x, bhi.y, bhi.z, bhi.w};
#pragma unroll
            for (int i = 0; i < TM; i++)
#pragma unroll
                for (int j = 0; j < TN; j++)
                    acc[i][j] = fmaf(a[i], b[j], acc[i][j]);
        }
        __syncthreads();
    }

    const float4 bs_lo = *(const float4*)(bsyn + col0 + tx * 4);
    const float4 bs_hi = *(const float4*)(bsyn + col0 + tx * 4 + 64);
    const float bsv[8] = {bs_lo.x, bs_lo.y, bs_lo.z, bs_lo.w, bs_hi.x, bs_hi.y, bs_hi.z, bs_hi.w};
#pragma unroll
    for (int i = 0; i < TM; i++) {
        const int r = row0 + ty * 4 + (i & 3) + ((i >> 2) << 6);
#pragma unroll
        for (int jg = 0; jg < 2; jg++) {
            const int c = col0 + tx * 4 + jg * 64;
            float4 v;
            v.x = acc[i][jg * 4 + 0] + bsv[jg * 4 + 0];
            v.y = acc[i][jg * 4 + 1] + bsv[jg * 4 + 1];
            v.z = acc[i][jg * 4 + 2] + bsv[jg * 4 + 2];
            v.w = acc[i][jg * 4 + 3] + bsv[jg * 4 + 3];
            *(float4*)(L1 + (size_t)r * O_DIM + c) = v;
        }
    }
}

// Stage 2: dual GEMM + epilogue + boundary flagging (fp32)
__global__ __launch_bounds__(256, 2)
void lsnn_stage2_f32(const float* __restrict__ L1,
                     const float* __restrict__ u_t, const float* __restrict__ b_t,
                     const float* __restrict__ spk,
                     const float* __restrict__ WTm, const float* __restrict__ bTm,
                     const float* __restrict__ WTa, const float* __restrict__ bTa,
                     float* __restrict__ out,
                     unsigned* __restrict__ cnt, unsigned* __restrict__ list,
                     unsigned cap) {
    __shared__ float A1s[BK][BM + 4];
    __shared__ float A2s[BK][BM + 4];
    __shared__ float Bms[BK][BN + 4];
    __shared__ float Bas[BK][BN + 4];

    const int tid = threadIdx.x;
    const int tx = tid & 15, ty = tid >> 4;
    const int row0 = blockIdx.y * BM, col0 = blockIdx.x * BN;
    const int ar = tid >> 2, ac = (tid & 3) << 2;

    float accM[TM][TN], accA[TM][TN];
#pragma unroll
    for (int i = 0; i < TM; i++)
#pragma unroll
        for (int j = 0; j < TN; j++) { accM[i][j] = 0.0f; accA[i][j] = 0.0f; }

    for (int k0 = 0; k0 < O_DIM; k0 += BK) {
        const size_t a0off = (size_t)(row0 + ar) * O_DIM + k0 + ac;
        const size_t a1off = (size_t)(row0 + ar + 64) * O_DIM + k0 + ac;
        const float4 l0 = *(const float4*)(L1 + a0off);
        const float4 l1 = *(const float4*)(L1 + a1off);
        const float4 u0 = *(const float4*)(u_t + a0off);
        const float4 u1 = *(const float4*)(u_t + a1off);
        const float4 t0 = *(const float4*)(b_t + a0off);
        const float4 t1 = *(const float4*)(b_t + a1off);
        A1s[ac + 0][ar] = l0.x + u0.x; A1s[ac + 1][ar] = l0.y + u0.y;
        A1s[ac + 2][ar] = l0.z + u0.z; A1s[ac + 3][ar] = l0.w + u0.w;
        A1s[ac + 0][ar + 64] = l1.x + u1.x; A1s[ac + 1][ar + 64] = l1.y + u1.y;
        A1s[ac + 2][ar + 64] = l1.z + u1.z; A1s[ac + 3][ar + 64] = l1.w + u1.w;
        A2s[ac + 0][ar] = l0.x + t0.x; A2s[ac + 1][ar] = l0.y + t0.y;
        A2s[ac + 2][ar] = l0.z + t0.z; A2s[ac + 3][ar] = l0.w + t0.w;
        A2s[ac + 0][ar + 64] = l1.x + t1.x; A2s[ac + 1][ar + 64] = l1.y + t1.y;
        A2s[ac + 2][ar + 64] = l1.z + t1.z; A2s[ac + 3][ar + 64] = l1.w + t1.w;

        const size_t b0off = (size_t)(col0 + ar) * O_DIM + k0 + ac;
        const size_t b1off = (size_t)(col0 + ar + 64) * O_DIM + k0 + ac;
        const float4 m0 = *(const float4*)(WTm + b0off);
        const float4 m1 = *(const float4*)(WTm + b1off);
        const float4 w0 = *(const float4*)(WTa + b0off);
        const float4 w1 = *(const float4*)(WTa + b1off);
        Bms[ac + 0][ar] = m0.x; Bms[ac + 1][ar] = m0.y; Bms[ac + 2][ar] = m0.z; Bms[ac + 3][ar] = m0.w;
        Bms[ac + 0][ar + 64] = m1.x; Bms[ac + 1][ar + 64] = m1.y; Bms[ac + 2][ar + 64] = m1.z; Bms[ac + 3][ar + 64] = m1.w;
        Bas[ac + 0][ar] = w0.x; Bas[ac + 1][ar] = w0.y; Bas[ac + 2][ar] = w0.z; Bas[ac + 3][ar] = w0.w;
        Bas[ac + 0][ar + 64] = w1.x; Bas[ac + 1][ar + 64] = w1.y; Bas[ac + 2][ar + 64] = w1.z; Bas[ac + 3][ar + 64] = w1.w;
        __syncthreads();
#pragma unroll 2
        for (int kk = 0; kk < BK; kk++) {
            const float4 a1lo = *(const float4*)&A1s[kk][ty * 4];
            const float4 a1hi = *(const float4*)&A1s[kk][ty * 4 + 64];
            const float4 a2lo = *(const float4*)&A2s[kk][ty * 4];
            const float4 a2hi = *(const float4*)&A2s[kk][ty * 4 + 64];
            const float4 bmlo = *(const float4*)&Bms[kk][tx * 4];
            const float4 bmhi = *(const float4*)&Bms[kk][tx * 4 + 64];
            const float4 balo = *(const float4*)&Bas[kk][tx * 4];
            const float4 bahi = *(const float4*)&Bas[kk][tx * 4 + 64];
            const float a1[8] = {a1lo.x, a1lo.y, a1lo.z, a1lo.w, a1hi.x, a1hi.y, a1hi.z, a1hi.w};
            const float a2[8] = {a2lo.x, a2lo.y, a2lo.z, a2lo.w, a2hi.x, a2hi.y, a2hi.z, a2hi.w};
            const float bm[8] = {bmlo.x, bmlo.y, bmlo.z, bmlo.w, bmhi.x, bmhi.y, bmhi.z, bmhi.w};
            const float ba[8] = {balo.x, balo.y, balo.z, balo.w, bahi.x, bahi.y, bahi.z, bahi.w};
#pragma unroll
            for (int i = 0; i < TM; i++)
#pragma unroll
                for (int j = 0; j < TN; j++) {
                    accM[i][j] = fmaf(a1[i], bm[j], accM[i][j]);
                    accA[i][j] = fmaf(a2[i], ba[j], accA[i][j]);
                }
        }
        __syncthreads();
    }

    const float4 bm_lo = *(const float4*)(bTm + col0 + tx * 4);
    const float4 bm_hi = *(const float4*)(bTm + col0 + tx * 4 + 64);
    const float4 ba_lo = *(const float4*)(bTa + col0 + tx * 4);
    const float4 ba_hi = *(const float4*)(bTa + col0 + tx * 4 + 64);
    const float bmv[8] = {bm_lo.x, bm_lo.y, bm_lo.z, bm_lo.w, bm_hi.x, bm_hi.y, bm_hi.z, bm_hi.w};
    const float bav[8] = {ba_lo.x, ba_lo.y, ba_lo.z, ba_lo.w, ba_hi.x, ba_hi.y, ba_hi.z, ba_hi.w};

#pragma unroll
    for (int i = 0; i < TM; i++) {
        const int r = row0 + ty * 4 + (i & 3) + ((i >> 2) << 6);
#pragma unroll
        for (int jg = 0; jg < 2; jg++) {
            const int c = col0 + tx * 4 + jg * 64;
            const size_t idx = (size_t)r * O_DIM + c;
            const float4 uv = *(const float4*)(u_t + idx);
            const float4 tv = *(const float4*)(b_t + idx);
            const float4 sv = *(const float4*)(spk + idx);
            const float4 lv = *(const float4*)(L1 + idx);
            const float us[4] = {uv.x, uv.y, uv.z, uv.w};
            const float ts[4] = {tv.x, tv.y, tv.z, tv.w};
            const float ss[4] = {sv.x, sv.y, sv.z, sv.w};
            const float ls[4] = {lv.x, lv.y, lv.z, lv.w};
            float ov[4];
#pragma unroll
            for (int j = 0; j < 4; j++) {
                const float zm = accM[i][jg * 4 + j] + bmv[jg * 4 + j];
                const float za = accA[i][jg * 4 + j] + bav[jg * 4 + j];
                const float inv_alpha = 1.0f + expf(-zm);           // 1/sigmoid(zm)
                const float rho = 1.0f / (1.0f + expf(-za));
                const float b_new = ss[j] + rho * (ts[j] - ss[j]);
                const float thr = 0.01f + 1.8f * b_new;
                const float u_new = us[j] + (ls[j] - us[j]) * inv_alpha;
                const float d = u_new - thr;
                ov[j] = d > 0.0f ? 1.0f : 0.0f;
                if (fabsf(d) < DELTA) {
                    const unsigned pos = atomicAdd(cnt, 1u);
                    if (pos < cap) list[pos] = (unsigned)(idx + j);
                }
            }
            *(float4*)(out + idx) = make_float4(ov[0], ov[1], ov[2], ov[3]);
        }
    }
}

// Fixup: exact f64 recompute of flagged boundary elements.
__global__ __launch_bounds__(256)
void lsnn_fixup(const float* __restrict__ L1f,
                const float* __restrict__ X, const float* __restrict__ Wsyn,
                const float* __restrict__ bsyn,
                const float* __restrict__ u_t, const float* __restrict__ b_t,
                const float* __restrict__ spk,
                const float* __restrict__ WTm, const float* __restrict__ bTm,
                const float* __restrict__ WTa, const float* __restrict__ bTa,
                const unsigned* __restrict__ cnt, const unsigned* __restrict__ list,
                unsigned cap, float* __restrict__ out) {
    const unsigned n = min(*cnt, cap);
    const int lane = threadIdx.x & 63;
    const unsigned wid = (blockIdx.x * blockDim.x + threadIdx.x) >> 6;
    const unsigned nw = (gridDim.x * blockDim.x) >> 6;

    for (unsigned e = wid; e < n; e += nw) {
        const unsigned idx = list[e];
        const int b = idx >> 11;          // / O_DIM
        const int o = idx & (O_DIM - 1);  // % O_DIM

        double l1 = 0.0, zm = 0.0, za = 0.0;
        const float* xr = X + (size_t)b * I_DIM;
        const float* wr = Wsyn + (size_t)o * I_DIM;
        for (int k = lane; k < I_DIM; k += 64)
            l1 = fma((double)xr[k], (double)wr[k], l1);

        const float* lr = L1f + (size_t)b * O_DIM;
        const float* ur = u_t + (size_t)b * O_DIM;
        const float* tr = b_t + (size_t)b * O_DIM;
        const float* mr = WTm + (size_t)o * O_DIM;
        const float* ar = WTa + (size_t)o * O_DIM;
        for (int k = lane; k < O_DIM; k += 64) {
            const double l = (double)lr[k];
            zm = fma(l + (double)ur[k], (double)mr[k], zm);
            za = fma(l + (double)tr[k], (double)ar[k], za);
        }
#pragma unroll
        for (int off = 32; off > 0; off >>= 1) {
            l1 += __shfl_down(l1, off);
            zm += __shfl_down(zm, off);
            za += __shfl_down(za, off);
        }
        if (lane == 0) {
            l1 += (double)bsyn[o];
            zm += (double)bTm[o];
            za += (double)bTa[o];
            const double inv_alpha = 1.0 + exp(-zm);
            const double rho = 1.0 / (1.0 + exp(-za));
            const double bt = (double)b_t[idx];
            const double sp = (double)spk[idx];
            const double ut = (double)u_t[idx];
            const double b_new = sp + rho * (bt - sp);
            const double thr = 0.01 + 1.8 * b_new;
            const double u_new = ut + (l1 - ut) * inv_alpha;
            out[idx] = (u_new - thr > 0.0) ? 1.0f : 0.0f;
        }
    }
}

// ===========================================================================
// f64 fallback path (round-1 kernels, used only if ws is too small)
// ===========================================================================
#define FBM 64
#define FBN 64
#define FBK 16

__global__ __launch_bounds__(256)
void lsnn_l1_f64(const float* __restrict__ X, const float* __restrict__ Wsyn,
                 const float* __restrict__ bsyn, double* __restrict__ L1) {
    __shared__ double As[FBM][FBK + 1];
    __shared__ double Bs[FBN][FBK + 1];
    const int tid = threadIdx.x;
    const int tx = tid & 15, ty = tid >> 4;
    const int row0 = blockIdx.y * FBM, col0 = blockIdx.x * FBN;
    double acc[4][4] = {};
    const int lr = (tid * 4) >> 4, lc = (tid * 4) & 15;
    for (int k0 = 0; k0 < I_DIM; k0 += FBK) {
        const float4 av = *(const float4*)(X + (size_t)(row0 + lr) * I_DIM + k0 + lc);
        const float4 bv = *(const float4*)(Wsyn + (size_t)(col0 + lr) * I_DIM + k0 + lc);
        As[lr][lc + 0] = av.x; As[lr][lc + 1] = av.y; As[lr][lc + 2] = av.z; As[lr][lc + 3] = av.w;
        Bs[lr][lc + 0] = bv.x; Bs[lr][lc + 1] = bv.y; Bs[lr][lc + 2] = bv.z; Bs[lr][lc + 3] = bv.w;
        __syncthreads();
#pragma unroll
        for (int kk = 0; kk < FBK; kk++) {
            double a[4], b[4];
#pragma unroll
            for (int i = 0; i < 4; i++) a[i] = As[ty + 16 * i][kk];
#pragma unroll
            for (int j = 0; j < 4; j++) b[j] = Bs[tx + 16 * j][kk];
#pragma unroll
            for (int i = 0; i < 4; i++)
#pragma unroll
                for (int j = 0; j < 4; j++) acc[i][j] = fma(a[i], b[j], acc[i][j]);
        }
        __syncthreads();
    }
#pragma unroll
    for (int i = 0; i < 4; i++)
#pragma unroll
        for (int j = 0; j < 4; j++)
            L1[(size_t)(row0 + ty + 16 * i) * O_DIM + col0 + tx + 16 * j] =
                acc[i][j] + (double)bsyn[col0 + tx + 16 * j];
}

__global__ __launch_bounds__(256)
void lsnn_stage2_f64(const double* __restrict__ L1,
                     const float* __restrict__ u_t, const float* __restrict__ b_t,
                     const float* __restrict__ spk,
                     const float* __restrict__ WTm, const float* __restrict__ bTm,
                     const float* __restrict__ WTa, const float* __restrict__ bTa,
                     float* __restrict__ out) {
    __shared__ double A1s[FBM][FBK + 1];
    __shared__ double A2s[FBM][FBK + 1];
    __shared__ double Bms[FBN][FBK + 1];
    __shared__ double Bas[FBN][FBK + 1];
    const int tid = threadIdx.x;
    const int tx = tid & 15, ty = tid >> 4;
    const int row0 = blockIdx.y * FBM, col0 = blockIdx.x * FBN;
    double accM[4][4] = {}, accA[4][4] = {};
    const int lr = (tid * 4) >> 4, lc = (tid * 4) & 15;
    for (int k0 = 0; k0 < O_DIM; k0 += FBK) {
        const size_t arow = (size_t)(row0 + lr) * O_DIM + k0 + lc;
        const double4 lv = *(const double4*)(L1 + arow);
        const float4 uv = *(const float4*)(u_t + arow);
        const float4 bv = *(const float4*)(b_t + arow);
        A1s[lr][lc + 0] = lv.x + (double)uv.x; A1s[lr][lc + 1] = lv.y + (double)uv.y;
        A1s[lr][lc + 2] = lv.z + (double)uv.z; A1s[lr][lc + 3] = lv.w + (double)uv.w;
        A2s[lr][lc + 0] = lv.x + (double)bv.x; A2s[lr][lc + 1] = lv.y + (double)bv.y;
        A2s[lr][lc + 2] = lv.z + (double)bv.z; A2s[lr][lc + 3] = lv.w + (double)bv.w;
        const size_t brow = (size_t)(col0 + lr) * O_DIM + k0 + lc;
        const float4 wm = *(const float4*)(WTm + brow);
        const float4 wa = *(const float4*)(WTa + brow);
        Bms[lr][lc + 0] = wm.x; Bms[lr][lc + 1] = wm.y; Bms[lr][lc + 2] = wm.z; Bms[lr][lc + 3] = wm.w;
        Bas[lr][lc + 0] = wa.x; Bas[lr][lc + 1] = wa.y; Bas[lr][lc + 2] = wa.z; Bas[lr][lc + 3] = wa.w;
        __syncthreads();
#pragma unroll
        for (int kk = 0; kk < FBK; kk++) {
            double a1[4], a2[4], bm[4], ba[4];
#pragma unroll
            for (int i = 0; i < 4; i++) { a1[i] = A1s[ty + 16 * i][kk]; a2[i] = A2s[ty + 16 * i][kk]; }
#pragma unroll
            for (int j = 0; j < 4; j++) { bm[j] = Bms[tx + 16 * j][kk]; ba[j] = Bas[tx + 16 * j][kk]; }
#pragma unroll
            for (int i = 0; i < 4; i++)
#pragma unroll
                for (int j = 0; j < 4; j++) {
                    accM[i][j] = fma(a1[i], bm[j], accM[i][j]);
                    accA[i][j] = fma(a2[i], ba[j], accA[i][j]);
                }
        }
        __syncthreads();
    }
#pragma unroll
    for (int i = 0; i < 4; i++)
#pragma unroll
        for (int j = 0; j < 4; j++) {
            const int r = row0 + ty + 16 * i, c = col0 + tx + 16 * j;
            const size_t idx = (size_t)r * O_DIM + c;
            const double zm = accM[i][j] + (double)bTm[c];
            const double za = accA[i][j] + (double)bTa[c];
            const double rho = 1.0 / (1.0 + exp(-za));
            const double b_new = (double)spk[idx] + rho * ((double)b_t[idx] - (double)spk[idx]);
            const double thr = 0.01 + 1.8 * b_new;
            const double u_new = (double)u_t[idx] + (L1[idx] - (double)u_t[idx]) * (1.0 + exp(-zm));
            out[idx] = (u_new - thr > 0.0) ? 1.0f : 0.0f;
        }
}

// ===========================================================================
extern "C" void kernel_launch(void* const* d_in, const int* in_sizes, int n_in,
                              void* d_out, int out_size, void* d_ws, size_t ws_size,
                              hipStream_t stream) {
    const float* x    = (const float*)d_in[0];
    const float* u_t  = (const float*)d_in[1];
    const float* b_t  = (const float*)d_in[2];
    const float* spk  = (const float*)d_in[3];
    const float* Wsyn = (const float*)d_in[4];
    const float* bsyn = (const float*)d_in[5];
    const float* WTm  = (const float*)d_in[6];
    const float* bTm  = (const float*)d_in[7];
    const float* WTa  = (const float*)d_in[8];
    const float* bTa  = (const float*)d_in[9];
    float* out = (float*)d_out;

    if (ws_size >= LIST_OFF + (1u << 20)) {
        // fp32 fast path + f64 boundary fixup
        float* L1 = (float*)d_ws;
        unsigned* cnt = (unsigned*)((char*)d_ws + CNT_OFF);
        unsigned* list = (unsigned*)((char*)d_ws + LIST_OFF);
        const unsigned cap = (unsigned)((ws_size - LIST_OFF) / sizeof(unsigned));

        hipMemsetAsync(cnt, 0, sizeof(unsigned), stream);
        dim3 blk(256);
        dim3 grd(O_DIM / BN, B_DIM / BM);   // (16, 32)
        lsnn_l1_f32<<<grd, blk, 0, stream>>>(x, Wsyn, bsyn, L1);
        lsnn_stage2_f32<<<grd, blk, 0, stream>>>(L1, u_t, b_t, spk, WTm, bTm, WTa, bTa,
                                                 out, cnt, list, cap);
        lsnn_fixup<<<dim3(128), blk, 0, stream>>>(L1, x, Wsyn, bsyn, u_t, b_t, spk,
                                                  WTm, bTm, WTa, bTa, cnt, list, cap, out);
    } else if (ws_size >= (size_t)B_DIM * O_DIM * sizeof(double)) {
        double* L1 = (double*)d_ws;
        dim3 blk(256);
        dim3 grd(O_DIM / FBN, B_DIM / FBM);
        lsnn_l1_f64<<<grd, blk, 0, stream>>>(x, Wsyn, bsyn, L1);
        lsnn_stage2_f64<<<grd, blk, 0, stream>>>(L1, u_t, b_t, spk, WTm, bTm, WTa, bTa, out);
    }
}

// Round 4
// 468.894 us; speedup vs baseline: 8.5791x; 3.0015x over previous
//
#include <hip/hip_runtime.h>
#include <cmath>

#define B_DIM 4096
#define O_DIM 2048
#define I_DIM 2048

typedef _Float16 f16x8 __attribute__((ext_vector_type(8)));
typedef float f32x4 __attribute__((ext_vector_type(4)));
typedef unsigned int uint;

#define L1_BYTES ((size_t)B_DIM * O_DIM * sizeof(float))  /* 32 MB */
#define CNT_OFF  L1_BYTES
#define LIST_OFF (L1_BYTES + 256)
#define WSCALE   64.0f
#define WDESCALE 0.015625f

// Split 8 f32 (two float4) into hi/lo f16 pairs, packed as uint4 each.
// x ~= hi + lo with |x - hi - lo| <~ 2^-22 |x|  (RTZ both stages).
__device__ __forceinline__ void split8(const float4 a, const float4 b,
                                       uint4& hi, uint4& lo) {
    auto h0 = __builtin_amdgcn_cvt_pkrtz(a.x, a.y);
    auto h1 = __builtin_amdgcn_cvt_pkrtz(a.z, a.w);
    auto h2 = __builtin_amdgcn_cvt_pkrtz(b.x, b.y);
    auto h3 = __builtin_amdgcn_cvt_pkrtz(b.z, b.w);
    auto l0 = __builtin_amdgcn_cvt_pkrtz(a.x - (float)h0[0], a.y - (float)h0[1]);
    auto l1 = __builtin_amdgcn_cvt_pkrtz(a.z - (float)h1[0], a.w - (float)h1[1]);
    auto l2 = __builtin_amdgcn_cvt_pkrtz(b.x - (float)h2[0], b.y - (float)h2[1]);
    auto l3 = __builtin_amdgcn_cvt_pkrtz(b.z - (float)h3[0], b.w - (float)h3[1]);
    hi.x = __builtin_bit_cast(uint, h0); hi.y = __builtin_bit_cast(uint, h1);
    hi.z = __builtin_bit_cast(uint, h2); hi.w = __builtin_bit_cast(uint, h3);
    lo.x = __builtin_bit_cast(uint, l0); lo.y = __builtin_bit_cast(uint, l1);
    lo.z = __builtin_bit_cast(uint, l2); lo.w = __builtin_bit_cast(uint, l3);
}

__device__ __forceinline__ float4 add4(const float4 a, const float4 b) {
    return make_float4(a.x + b.x, a.y + b.y, a.z + b.z, a.w + b.w);
}
__device__ __forceinline__ float4 mul64(const float4 a) {
    return make_float4(a.x * WSCALE, a.y * WSCALE, a.z * WSCALE, a.w * WSCALE);
}

// ===========================================================================
// GEMM1: L1[b,o] = X[b,:].Wsyn[o,:] + bsyn[o]   (split-f16 MFMA, fp32-class)
// 128x128 tile, BK=32, 256 thr (4 waves, 64x64 each)
// ===========================================================================
__global__ __launch_bounds__(256)
void gemm1_mfma(const float* __restrict__ X, const float* __restrict__ W,
                const float* __restrict__ bias, float* __restrict__ L1) {
    __shared__ uint Ah[128][20], Al[128][20], Bh[128][20], Bl[128][20];

    const int tid = threadIdx.x;
    const int lane = tid & 63;
    const int wid = tid >> 6;
    const int wm = wid >> 1, wn = wid & 1;

    int sid = blockIdx.x;
    sid = (sid & 7) * 64 + (sid >> 3);        // XCD swizzle (512 % 8 == 0)
    const int bx = sid & 15, by = sid >> 4;   // 16 N-tiles, 32 M-tiles
    const int row0 = by * 128, col0 = bx * 128;

    const int srow = tid >> 1;                // 0..127
    const int skb = (tid & 1) * 16;           // f32 k-offset
    const int swc = (tid & 1) * 8;            // u32 col in LDS

    const float* pA = X + (size_t)(row0 + srow) * I_DIM + skb;
    const float* pB = W + (size_t)(col0 + srow) * I_DIM + skb;

    f32x4 acc[4][4];
#pragma unroll
    for (int i = 0; i < 4; i++)
#pragma unroll
        for (int j = 0; j < 4; j++)
#pragma unroll
            for (int r = 0; r < 4; r++) acc[i][j][r] = 0.0f;

    float4 pa0 = *(const float4*)(pA + 0),  pa1 = *(const float4*)(pA + 4);
    float4 pa2 = *(const float4*)(pA + 8),  pa3 = *(const float4*)(pA + 12);
    float4 pb0 = *(const float4*)(pB + 0),  pb1 = *(const float4*)(pB + 4);
    float4 pb2 = *(const float4*)(pB + 8),  pb3 = *(const float4*)(pB + 12);

    const int fr = lane & 15;
    const int kq = (lane >> 4) * 4;           // u32 k-slot

    for (int t = 0; t < I_DIM / 32; t++) {
        uint4 ahi0, alo0, ahi1, alo1, bhi0, blo0, bhi1, blo1;
        split8(pa0, pa1, ahi0, alo0);
        split8(pa2, pa3, ahi1, alo1);
        split8(mul64(pb0), mul64(pb1), bhi0, blo0);
        split8(mul64(pb2), mul64(pb3), bhi1, blo1);
        __syncthreads();
        *(uint4*)&Ah[srow][swc] = ahi0;  *(uint4*)&Ah[srow][swc + 4] = ahi1;
        *(uint4*)&Al[srow][swc] = alo0;  *(uint4*)&Al[srow][swc + 4] = alo1;
        *(uint4*)&Bh[srow][swc] = bhi0;  *(uint4*)&Bh[srow][swc + 4] = bhi1;
        *(uint4*)&Bl[srow][swc] = blo0;  *(uint4*)&Bl[srow][swc + 4] = blo1;
        __syncthreads();
        if (t + 1 < I_DIM / 32) {
            const float* nA = pA + (t + 1) * 32;
            const float* nB = pB + (t + 1) * 32;
            pa0 = *(const float4*)(nA + 0);  pa1 = *(const float4*)(nA + 4);
            pa2 = *(const float4*)(nA + 8);  pa3 = *(const float4*)(nA + 12);
            pb0 = *(const float4*)(nB + 0);  pb1 = *(const float4*)(nB + 4);
            pb2 = *(const float4*)(nB + 8);  pb3 = *(const float4*)(nB + 12);
        }
        f16x8 ah_[4], al_[4], bh_[4], bl_[4];
#pragma unroll
        for (int mi = 0; mi < 4; mi++) {
            const int r = wm * 64 + mi * 16 + fr;
            ah_[mi] = *(const f16x8*)&Ah[r][kq];
            al_[mi] = *(const f16x8*)&Al[r][kq];
        }
#pragma unroll
        for (int ni = 0; ni < 4; ni++) {
            const int r = wn * 64 + ni * 16 + fr;
            bh_[ni] = *(const f16x8*)&Bh[r][kq];
            bl_[ni] = *(const f16x8*)&Bl[r][kq];
        }
#pragma unroll
        for (int mi = 0; mi < 4; mi++)
#pragma unroll
            for (int ni = 0; ni < 4; ni++) {
                acc[mi][ni] = __builtin_amdgcn_mfma_f32_16x16x32_f16(ah_[mi], bh_[ni], acc[mi][ni], 0, 0, 0);
                acc[mi][ni] = __builtin_amdgcn_mfma_f32_16x16x32_f16(ah_[mi], bl_[ni], acc[mi][ni], 0, 0, 0);
                acc[mi][ni] = __builtin_amdgcn_mfma_f32_16x16x32_f16(al_[mi], bh_[ni], acc[mi][ni], 0, 0, 0);
            }
    }

#pragma unroll
    for (int ni = 0; ni < 4; ni++) {
        const int col = col0 + wn * 64 + ni * 16 + fr;
        const float bv = bias[col];
#pragma unroll
        for (int mi = 0; mi < 4; mi++) {
            const int rb = row0 + wm * 64 + mi * 16 + ((lane >> 4) << 2);
#pragma unroll
            for (int r = 0; r < 4; r++)
                L1[(size_t)(rb + r) * O_DIM + col] = acc[mi][ni][r] * WDESCALE + bv;
        }
    }
}

// ===========================================================================
// Stage 2: fused dual GEMM (zm, za) + LSNN epilogue + boundary flagging
// 128x128 tile, BK=32, 512 thr (8 waves, 64x32 each)
// ===========================================================================
__global__ __launch_bounds__(512)
void stage2_mfma(const float* __restrict__ L1,
                 const float* __restrict__ u_t, const float* __restrict__ b_t,
                 const float* __restrict__ spk,
                 const float* __restrict__ WTm, const float* __restrict__ bTm,
                 const float* __restrict__ WTa, const float* __restrict__ bTa,
                 float* __restrict__ out,
                 unsigned* __restrict__ cnt, unsigned* __restrict__ list,
                 unsigned cap) {
    __shared__ uint A1h[128][20], A1l[128][20], A2h[128][20], A2l[128][20];
    __shared__ uint Mh[128][20],  Ml[128][20],  Gh[128][20],  Gl[128][20];

    const int tid = threadIdx.x;
    const int lane = tid & 63;
    const int wid = tid >> 6;                 // 0..7
    const int wm = wid >> 2;                  // 0..1 -> m-offset *64
    const int wn = wid & 3;                   // 0..3 -> n-offset *32

    int sid = blockIdx.x;
    sid = (sid & 7) * 64 + (sid >> 3);
    const int bx = sid & 15, by = sid >> 4;
    const int row0 = by * 128, col0 = bx * 128;

    const int srow = tid >> 2;                // 0..127
    const int skb = (tid & 3) * 8;            // f32 k-offset
    const int swc = (tid & 3) * 4;            // u32 col in LDS

    const float* pL = L1  + (size_t)(row0 + srow) * O_DIM + skb;
    const float* pU = u_t + (size_t)(row0 + srow) * O_DIM + skb;
    const float* pT = b_t + (size_t)(row0 + srow) * O_DIM + skb;
    const float* pM = WTm + (size_t)(col0 + srow) * O_DIM + skb;
    const float* pG = WTa + (size_t)(col0 + srow) * O_DIM + skb;

    f32x4 accM[4][2], accA[4][2];
#pragma unroll
    for (int i = 0; i < 4; i++)
#pragma unroll
        for (int j = 0; j < 2; j++)
#pragma unroll
            for (int r = 0; r < 4; r++) { accM[i][j][r] = 0.0f; accA[i][j][r] = 0.0f; }

    float4 lq0 = *(const float4*)(pL + 0), lq1 = *(const float4*)(pL + 4);
    float4 uq0 = *(const float4*)(pU + 0), uq1 = *(const float4*)(pU + 4);
    float4 tq0 = *(const float4*)(pT + 0), tq1 = *(const float4*)(pT + 4);
    float4 mq0 = *(const float4*)(pM + 0), mq1 = *(const float4*)(pM + 4);
    float4 gq0 = *(const float4*)(pG + 0), gq1 = *(const float4*)(pG + 4);

    const int fr = lane & 15;
    const int kq = (lane >> 4) * 4;

    for (int t = 0; t < O_DIM / 32; t++) {
        uint4 A1hi, A1lo, A2hi, A2lo, Mhi, Mlo, Ghi, Glo;
        split8(add4(lq0, uq0), add4(lq1, uq1), A1hi, A1lo);
        split8(add4(lq0, tq0), add4(lq1, tq1), A2hi, A2lo);
        split8(mul64(mq0), mul64(mq1), Mhi, Mlo);
        split8(mul64(gq0), mul64(gq1), Ghi, Glo);
        __syncthreads();
        *(uint4*)&A1h[srow][swc] = A1hi;  *(uint4*)&A1l[srow][swc] = A1lo;
        *(uint4*)&A2h[srow][swc] = A2hi;  *(uint4*)&A2l[srow][swc] = A2lo;
        *(uint4*)&Mh[srow][swc]  = Mhi;   *(uint4*)&Ml[srow][swc]  = Mlo;
        *(uint4*)&Gh[srow][swc]  = Ghi;   *(uint4*)&Gl[srow][swc]  = Glo;
        __syncthreads();
        if (t + 1 < O_DIM / 32) {
            const int o = (t + 1) * 32;
            lq0 = *(const float4*)(pL + o);     lq1 = *(const float4*)(pL + o + 4);
            uq0 = *(const float4*)(pU + o);     uq1 = *(const float4*)(pU + o + 4);
            tq0 = *(const float4*)(pT + o);     tq1 = *(const float4*)(pT + o + 4);
            mq0 = *(const float4*)(pM + o);     mq1 = *(const float4*)(pM + o + 4);
            gq0 = *(const float4*)(pG + o);     gq1 = *(const float4*)(pG + o + 4);
        }
        {   // GEMM M (alpha logits)
            f16x8 ah_[4], al_[4], bh_[2], bl_[2];
#pragma unroll
            for (int mi = 0; mi < 4; mi++) {
                const int r = wm * 64 + mi * 16 + fr;
                ah_[mi] = *(const f16x8*)&A1h[r][kq];
                al_[mi] = *(const f16x8*)&A1l[r][kq];
            }
#pragma unroll
            for (int ni = 0; ni < 2; ni++) {
                const int r = wn * 32 + ni * 16 + fr;
                bh_[ni] = *(const f16x8*)&Mh[r][kq];
                bl_[ni] = *(const f16x8*)&Ml[r][kq];
            }
#pragma unroll
            for (int mi = 0; mi < 4; mi++)
#pragma unroll
                for (int ni = 0; ni < 2; ni++) {
                    accM[mi][ni] = __builtin_amdgcn_mfma_f32_16x16x32_f16(ah_[mi], bh_[ni], accM[mi][ni], 0, 0, 0);
                    accM[mi][ni] = __builtin_amdgcn_mfma_f32_16x16x32_f16(ah_[mi], bl_[ni], accM[mi][ni], 0, 0, 0);
                    accM[mi][ni] = __builtin_amdgcn_mfma_f32_16x16x32_f16(al_[mi], bh_[ni], accM[mi][ni], 0, 0, 0);
                }
        }
        {   // GEMM A (rho logits)
            f16x8 ah_[4], al_[4], bh_[2], bl_[2];
#pragma unroll
            for (int mi = 0; mi < 4; mi++) {
                const int r = wm * 64 + mi * 16 + fr;
                ah_[mi] = *(const f16x8*)&A2h[r][kq];
                al_[mi] = *(const f16x8*)&A2l[r][kq];
            }
#pragma unroll
            for (int ni = 0; ni < 2; ni++) {
                const int r = wn * 32 + ni * 16 + fr;
                bh_[ni] = *(const f16x8*)&Gh[r][kq];
                bl_[ni] = *(const f16x8*)&Gl[r][kq];
            }
#pragma unroll
            for (int mi = 0; mi < 4; mi++)
#pragma unroll
                for (int ni = 0; ni < 2; ni++) {
                    accA[mi][ni] = __builtin_amdgcn_mfma_f32_16x16x32_f16(ah_[mi], bh_[ni], accA[mi][ni], 0, 0, 0);
                    accA[mi][ni] = __builtin_amdgcn_mfma_f32_16x16x32_f16(ah_[mi], bl_[ni], accA[mi][ni], 0, 0, 0);
                    accA[mi][ni] = __builtin_amdgcn_mfma_f32_16x16x32_f16(al_[mi], bh_[ni], accA[mi][ni], 0, 0, 0);
                }
        }
    }

    // Epilogue: sigmoids, threshold, spike decision, sensitivity-scaled flagging
#pragma unroll
    for (int ni = 0; ni < 2; ni++) {
        const int col = col0 + wn * 32 + ni * 16 + fr;
        const float bm = bTm[col], bg = bTa[col];
#pragma unroll
        for (int mi = 0; mi < 4; mi++) {
            const int rb = row0 + wm * 64 + mi * 16 + ((lane >> 4) << 2);
#pragma unroll
            for (int r = 0; r < 4; r++) {
                const size_t idx = (size_t)(rb + r) * O_DIM + col;
                const float zm = accM[mi][ni][r] * WDESCALE + bm;
                const float za = accA[mi][ni][r] * WDESCALE + bg;
                const float ut = u_t[idx], bt = b_t[idx];
                const float sp = spk[idx], l1 = L1[idx];
                const float ea  = expf(-zm);               // inv_alpha = 1 + ea
                const float rho = 1.0f / (1.0f + expf(-za));
                const float bn  = sp + rho * (bt - sp);
                const float thr = 0.01f + 1.8f * bn;
                const float un  = ut + (l1 - ut) * (1.0f + ea);
                const float d   = un - thr;
                out[idx] = d > 0.0f ? 1.0f : 0.0f;
                const float tol = 2e-4f + 1e-4f * ea * (1.0f + fabsf(l1 - ut))
                                + 2e-4f * fabsf(bt - sp);
                if (fabsf(d) < tol) {
                    const unsigned pos = atomicAdd(cnt, 1u);
                    if (pos < cap) list[pos] = (unsigned)idx;
                }
            }
        }
    }
}

// ===========================================================================
// Fixup: exact f64 recompute of flagged boundary elements (validated round 2)
// ===========================================================================
__global__ __launch_bounds__(256)
void lsnn_fixup(const float* __restrict__ L1f,
                const float* __restrict__ X, const float* __restrict__ Wsyn,
                const float* __restrict__ bsyn,
                const float* __restrict__ u_t, const float* __restrict__ b_t,
                const float* __restrict__ spk,
                const float* __restrict__ WTm, const float* __restrict__ bTm,
                const float* __restrict__ WTa, const float* __restrict__ bTa,
                const unsigned* __restrict__ cnt, const unsigned* __restrict__ list,
                unsigned cap, float* __restrict__ out) {
    const unsigned nc = *cnt;
    const unsigned n = nc < cap ? nc : cap;
    const int lane = threadIdx.x & 63;
    const unsigned wid = (blockIdx.x * blockDim.x + threadIdx.x) >> 6;
    const unsigned nw = (gridDim.x * blockDim.x) >> 6;

    for (unsigned e = wid; e < n; e += nw) {
        const unsigned idx = list[e];
        const int b = idx >> 11;
        const int o = idx & (O_DIM - 1);

        double l1 = 0.0, zm = 0.0, za = 0.0;
        const float* xr = X + (size_t)b * I_DIM;
        const float* wr = Wsyn + (size_t)o * I_DIM;
        for (int k = lane; k < I_DIM; k += 64)
            l1 = fma((double)xr[k], (double)wr[k], l1);

        const float* lr = L1f + (size_t)b * O_DIM;
        const float* ur = u_t + (size_t)b * O_DIM;
        const float* tr = b_t + (size_t)b * O_DIM;
        const float* mr = WTm + (size_t)o * O_DIM;
        const float* ar = WTa + (size_t)o * O_DIM;
        for (int k = lane; k < O_DIM; k += 64) {
            const double l = (double)lr[k];
            zm = fma(l + (double)ur[k], (double)mr[k], zm);
            za = fma(l + (double)tr[k], (double)ar[k], za);
        }
#pragma unroll
        for (int off = 32; off > 0; off >>= 1) {
            l1 += __shfl_down(l1, off);
            zm += __shfl_down(zm, off);
            za += __shfl_down(za, off);
        }
        if (lane == 0) {
            l1 += (double)bsyn[o];
            zm += (double)bTm[o];
            za += (double)bTa[o];
            const double inv_alpha = 1.0 + exp(-zm);
            const double rho = 1.0 / (1.0 + exp(-za));
            const double bt = (double)b_t[idx];
            const double sp = (double)spk[idx];
            const double ut = (double)u_t[idx];
            const double b_new = sp + rho * (bt - sp);
            const double thr = 0.01 + 1.8 * b_new;
            const double u_new = ut + (l1 - ut) * inv_alpha;
            out[idx] = (u_new - thr > 0.0) ? 1.0f : 0.0f;
        }
    }
}

// ===========================================================================
extern "C" void kernel_launch(void* const* d_in, const int* in_sizes, int n_in,
                              void* d_out, int out_size, void* d_ws, size_t ws_size,
                              hipStream_t stream) {
    const float* x    = (const float*)d_in[0];
    const float* u_t  = (const float*)d_in[1];
    const float* b_t  = (const float*)d_in[2];
    const float* spk  = (const float*)d_in[3];
    const float* Wsyn = (const float*)d_in[4];
    const float* bsyn = (const float*)d_in[5];
    const float* WTm  = (const float*)d_in[6];
    const float* bTm  = (const float*)d_in[7];
    const float* WTa  = (const float*)d_in[8];
    const float* bTa  = (const float*)d_in[9];
    float* out = (float*)d_out;

    if (ws_size < LIST_OFF + (1u << 16)) return;  // cannot happen (ws >= 64 MB observed)

    float* L1 = (float*)d_ws;
    unsigned* cnt  = (unsigned*)((char*)d_ws + CNT_OFF);
    unsigned* list = (unsigned*)((char*)d_ws + LIST_OFF);
    const unsigned cap = (unsigned)((ws_size - LIST_OFF) / sizeof(unsigned));

    (void)hipMemsetAsync(cnt, 0, sizeof(unsigned), stream);
    gemm1_mfma<<<dim3(512), dim3(256), 0, stream>>>(x, Wsyn, bsyn, L1);
    stage2_mfma<<<dim3(512), dim3(512), 0, stream>>>(L1, u_t, b_t, spk,
                                                     WTm, bTm, WTa, bTa,
                                                     out, cnt, list, cap);
    lsnn_fixup<<<dim3(256), dim3(256), 0, stream>>>(L1, x, Wsyn, bsyn, u_t, b_t, spk,
                                                    WTm, bTm, WTa, bTa, cnt, list, cap, out);
}

// Round 5
// 301.114 us; speedup vs baseline: 13.3594x; 1.5572x over previous
//
#include <hip/hip_runtime.h>
#include <cmath>

#define B_DIM 4096
#define O_DIM 2048
#define I_DIM 2048

typedef _Float16 f16x8 __attribute__((ext_vector_type(8)));
typedef float f32x4 __attribute__((ext_vector_type(4)));
typedef unsigned int uint;
typedef unsigned short ushort;

#define WSCALE   64.0f
#define WDESCALE 0.015625f

// ws layout (requires >= ~49 MB; observed >= 64 MB)
#define L1H_OFF  ((size_t)0)                        // 4096*2048 ushort = 16 MB
#define L1L_OFF  ((size_t)16 * 1024 * 1024)         // 16 MB
#define MH_OFF   ((size_t)32 * 1024 * 1024)         // 2048*2048 ushort = 8 MB
#define ML_OFF   ((size_t)40 * 1024 * 1024)         // 8 MB
#define FLAG_OFF ((size_t)48 * 1024 * 1024)
#define CNT_OFF  (FLAG_OFF + 4)
#define LIST_OFF (FLAG_OFF + 256)

// Swizzled LDS tile: [128 rows][16 dwords] (K=32 f16). slot s in 0..3 holds
// 8 halves; physical slot = s ^ ((r>>1)&3). Bank-balanced for b128 r/w.
__device__ __forceinline__ int TP(int r, int s) {
    return r * 16 + (((s ^ ((r >> 1) & 3))) << 2);
}

__device__ __forceinline__ float h2f(ushort u) {
    _Float16 h = __builtin_bit_cast(_Float16, u);
    return (float)h;
}

// Split 8 f32 into hi/lo f16 (RTZ both stages), packed 8 halves per uint4.
__device__ __forceinline__ void split8(const float4 a, const float4 b,
                                       uint4& hi, uint4& lo) {
    auto h0 = __builtin_amdgcn_cvt_pkrtz(a.x, a.y);
    auto h1 = __builtin_amdgcn_cvt_pkrtz(a.z, a.w);
    auto h2 = __builtin_amdgcn_cvt_pkrtz(b.x, b.y);
    auto h3 = __builtin_amdgcn_cvt_pkrtz(b.z, b.w);
    auto l0 = __builtin_amdgcn_cvt_pkrtz(a.x - (float)h0[0], a.y - (float)h0[1]);
    auto l1 = __builtin_amdgcn_cvt_pkrtz(a.z - (float)h1[0], a.w - (float)h1[1]);
    auto l2 = __builtin_amdgcn_cvt_pkrtz(b.x - (float)h2[0], b.y - (float)h2[1]);
    auto l3 = __builtin_amdgcn_cvt_pkrtz(b.z - (float)h3[0], b.w - (float)h3[1]);
    hi.x = __builtin_bit_cast(uint, h0); hi.y = __builtin_bit_cast(uint, h1);
    hi.z = __builtin_bit_cast(uint, h2); hi.w = __builtin_bit_cast(uint, h3);
    lo.x = __builtin_bit_cast(uint, l0); lo.y = __builtin_bit_cast(uint, l1);
    lo.z = __builtin_bit_cast(uint, l2); lo.w = __builtin_bit_cast(uint, l3);
}

__device__ __forceinline__ float4 add4(const float4 a, const float4 b) {
    return make_float4(a.x + b.x, a.y + b.y, a.z + b.z, a.w + b.w);
}
__device__ __forceinline__ float4 mul64(const float4 a) {
    return make_float4(a.x * WSCALE, a.y * WSCALE, a.z * WSCALE, a.w * WSCALE);
}
__device__ __forceinline__ void unpack8(const uint4 h, const uint4 l,
                                        float4& f0, float4& f1) {
    f0.x = h2f((ushort)(h.x & 0xffff)) + h2f((ushort)(l.x & 0xffff));
    f0.y = h2f((ushort)(h.x >> 16))    + h2f((ushort)(l.x >> 16));
    f0.z = h2f((ushort)(h.y & 0xffff)) + h2f((ushort)(l.y & 0xffff));
    f0.w = h2f((ushort)(h.y >> 16))    + h2f((ushort)(l.y >> 16));
    f1.x = h2f((ushort)(h.z & 0xffff)) + h2f((ushort)(l.z & 0xffff));
    f1.y = h2f((ushort)(h.z >> 16))    + h2f((ushort)(l.z >> 16));
    f1.z = h2f((ushort)(h.w & 0xffff)) + h2f((ushort)(l.w & 0xffff));
    f1.w = h2f((ushort)(h.w >> 16))    + h2f((ushort)(l.w >> 16));
}

// ===========================================================================
// Zero-check: set *flag != 0 if any of u_t, b_t, spk is nonzero.
// ===========================================================================
__global__ __launch_bounds__(256)
void zcheck(const float* __restrict__ u, const float* __restrict__ b,
            const float* __restrict__ s, uint* __restrict__ flag) {
    const size_t n4 = (size_t)B_DIM * O_DIM / 4;
    const size_t stride = (size_t)gridDim.x * blockDim.x;
    bool nz = false;
    for (size_t i = blockIdx.x * blockDim.x + threadIdx.x; i < n4; i += stride) {
        const float4 a = ((const float4*)u)[i];
        const float4 c = ((const float4*)b)[i];
        const float4 d = ((const float4*)s)[i];
        nz |= (a.x != 0.f) | (a.y != 0.f) | (a.z != 0.f) | (a.w != 0.f);
        nz |= (c.x != 0.f) | (c.y != 0.f) | (c.z != 0.f) | (c.w != 0.f);
        nz |= (d.x != 0.f) | (d.y != 0.f) | (d.z != 0.f) | (d.w != 0.f);
    }
    if (nz) atomicOr(flag, 1u);
}

// ===========================================================================
// Pre-split WTm*64 into hi/lo f16 planes.
// ===========================================================================
__global__ __launch_bounds__(256)
void wsplit(const float* __restrict__ W, ushort* __restrict__ Wh,
            ushort* __restrict__ Wl) {
    const size_t i = ((size_t)blockIdx.x * blockDim.x + threadIdx.x) * 8;
    const float4 a = *(const float4*)(W + i);
    const float4 b = *(const float4*)(W + i + 4);
    uint4 h, l;
    split8(mul64(a), mul64(b), h, l);
    *(uint4*)(Wh + i) = h;
    *(uint4*)(Wl + i) = l;
}

// ===========================================================================
// GEMM1: L1 = X.Wsyn^T + bsyn  (3-chain split-f16 MFMA), output = split planes
// 128x128 tile, BK=32, 256 thr (4 waves, 64x64 each), swizzled 32 KB LDS
// ===========================================================================
__global__ __launch_bounds__(256)
void gemm1_mfma(const float* __restrict__ X, const float* __restrict__ W,
                const float* __restrict__ bias,
                ushort* __restrict__ Lh, ushort* __restrict__ Ll) {
    __shared__ uint Ah[2048], Al[2048], Bh[2048], Bl[2048];

    const int tid = threadIdx.x;
    const int lane = tid & 63;
    const int wid = tid >> 6;
    const int wm = wid >> 1, wn = wid & 1;

    int sid = blockIdx.x;
    sid = (sid & 7) * 64 + (sid >> 3);        // XCD swizzle (512 % 8 == 0)
    const int bx = sid & 15, by = sid >> 4;
    const int row0 = by * 128, col0 = bx * 128;

    const int sr = tid >> 1;                  // 0..127
    const int kh = (tid & 1) * 16;            // f32/half offset in K-block
    const int s0 = (tid & 1) * 2;             // logical slot base

    const float* pA = X + (size_t)(row0 + sr) * I_DIM + kh;
    const float* pB = W + (size_t)(col0 + sr) * I_DIM + kh;

    f32x4 acc[4][4];
#pragma unroll
    for (int i = 0; i < 4; i++)
#pragma unroll
        for (int j = 0; j < 4; j++)
#pragma unroll
            for (int r = 0; r < 4; r++) acc[i][j][r] = 0.0f;

    float4 a0 = *(const float4*)(pA + 0), a1 = *(const float4*)(pA + 4);
    float4 a2 = *(const float4*)(pA + 8), a3 = *(const float4*)(pA + 12);
    float4 b0 = *(const float4*)(pB + 0), b1 = *(const float4*)(pB + 4);
    float4 b2 = *(const float4*)(pB + 8), b3 = *(const float4*)(pB + 12);

    const int fr = lane & 15;
    const int sl = lane >> 4;                 // logical k-slot 0..3

    for (int t = 0; t < I_DIM / 32; t++) {
        uint4 xh0, xl0, xh1, xl1, wh0, wl0, wh1, wl1;
        split8(a0, a1, xh0, xl0);
        split8(a2, a3, xh1, xl1);
        split8(mul64(b0), mul64(b1), wh0, wl0);
        split8(mul64(b2), mul64(b3), wh1, wl1);
        __syncthreads();
        *(uint4*)&Ah[TP(sr, s0)] = xh0;  *(uint4*)&Ah[TP(sr, s0 + 1)] = xh1;
        *(uint4*)&Al[TP(sr, s0)] = xl0;  *(uint4*)&Al[TP(sr, s0 + 1)] = xl1;
        *(uint4*)&Bh[TP(sr, s0)] = wh0;  *(uint4*)&Bh[TP(sr, s0 + 1)] = wh1;
        *(uint4*)&Bl[TP(sr, s0)] = wl0;  *(uint4*)&Bl[TP(sr, s0 + 1)] = wl1;
        __syncthreads();
        if (t + 1 < I_DIM / 32) {
            const float* nA = pA + (t + 1) * 32;
            const float* nB = pB + (t + 1) * 32;
            a0 = *(const float4*)(nA + 0); a1 = *(const float4*)(nA + 4);
            a2 = *(const float4*)(nA + 8); a3 = *(const float4*)(nA + 12);
            b0 = *(const float4*)(nB + 0); b1 = *(const float4*)(nB + 4);
            b2 = *(const float4*)(nB + 8); b3 = *(const float4*)(nB + 12);
        }
        f16x8 ah_[4], al_[4], bh_[4], bl_[4];
#pragma unroll
        for (int mi = 0; mi < 4; mi++) {
            const int r = wm * 64 + mi * 16 + fr;
            ah_[mi] = *(const f16x8*)&Ah[TP(r, sl)];
            al_[mi] = *(const f16x8*)&Al[TP(r, sl)];
        }
#pragma unroll
        for (int ni = 0; ni < 4; ni++) {
            const int r = wn * 64 + ni * 16 + fr;
            bh_[ni] = *(const f16x8*)&Bh[TP(r, sl)];
            bl_[ni] = *(const f16x8*)&Bl[TP(r, sl)];
        }
#pragma unroll
        for (int mi = 0; mi < 4; mi++)
#pragma unroll
            for (int ni = 0; ni < 4; ni++) {
                acc[mi][ni] = __builtin_amdgcn_mfma_f32_16x16x32_f16(ah_[mi], bh_[ni], acc[mi][ni], 0, 0, 0);
                acc[mi][ni] = __builtin_amdgcn_mfma_f32_16x16x32_f16(ah_[mi], bl_[ni], acc[mi][ni], 0, 0, 0);
                acc[mi][ni] = __builtin_amdgcn_mfma_f32_16x16x32_f16(al_[mi], bh_[ni], acc[mi][ni], 0, 0, 0);
            }
    }

#pragma unroll
    for (int ni = 0; ni < 4; ni++) {
        const int col = col0 + wn * 64 + ni * 16 + fr;
        const float bv = bias[col];
#pragma unroll
        for (int mi = 0; mi < 4; mi++) {
            const int rb = row0 + wm * 64 + mi * 16 + ((lane >> 4) << 2);
            float e[4];
#pragma unroll
            for (int r = 0; r < 4; r++) e[r] = acc[mi][ni][r] * WDESCALE + bv;
            auto hp0 = __builtin_amdgcn_cvt_pkrtz(e[0], e[1]);
            auto hp1 = __builtin_amdgcn_cvt_pkrtz(e[2], e[3]);
            auto lp0 = __builtin_amdgcn_cvt_pkrtz(e[0] - (float)hp0[0], e[1] - (float)hp0[1]);
            auto lp1 = __builtin_amdgcn_cvt_pkrtz(e[2] - (float)hp1[0], e[3] - (float)hp1[1]);
            const uint uh0 = __builtin_bit_cast(uint, hp0);
            const uint uh1 = __builtin_bit_cast(uint, hp1);
            const uint ul0 = __builtin_bit_cast(uint, lp0);
            const uint ul1 = __builtin_bit_cast(uint, lp1);
            Lh[(size_t)(rb + 0) * O_DIM + col] = (ushort)(uh0 & 0xffff);
            Lh[(size_t)(rb + 1) * O_DIM + col] = (ushort)(uh0 >> 16);
            Lh[(size_t)(rb + 2) * O_DIM + col] = (ushort)(uh1 & 0xffff);
            Lh[(size_t)(rb + 3) * O_DIM + col] = (ushort)(uh1 >> 16);
            Ll[(size_t)(rb + 0) * O_DIM + col] = (ushort)(ul0 & 0xffff);
            Ll[(size_t)(rb + 1) * O_DIM + col] = (ushort)(ul0 >> 16);
            Ll[(size_t)(rb + 2) * O_DIM + col] = (ushort)(ul1 & 0xffff);
            Ll[(size_t)(rb + 3) * O_DIM + col] = (ushort)(ul1 >> 16);
        }
    }
}

// ===========================================================================
// Stage-2 FAST path (u=b=spk all zero): zm = L1.WTm^T + bTm only; thr = 0.01.
// Pure-copy staging from pre-split planes; 3-chain; swizzled 32 KB LDS.
// ===========================================================================
__global__ __launch_bounds__(256)
void stage2_fast(const ushort* __restrict__ Lhp, const ushort* __restrict__ Llp,
                 const ushort* __restrict__ Mhp, const ushort* __restrict__ Mlp,
                 const float* __restrict__ bTm, float* __restrict__ out,
                 const uint* __restrict__ flag,
                 uint* __restrict__ cnt, uint* __restrict__ list, uint cap) {
    if (*flag != 0) return;

    __shared__ uint LhT[2048], LlT[2048], MhT[2048], MlT[2048];

    const int tid = threadIdx.x;
    const int lane = tid & 63;
    const int wid = tid >> 6;
    const int wm = wid >> 1, wn = wid & 1;

    int sid = blockIdx.x;
    sid = (sid & 7) * 64 + (sid >> 3);
    const int bx = sid & 15, by = sid >> 4;
    const int row0 = by * 128, col0 = bx * 128;

    // staging: thread covers uint4 indices g = tid*2 + {0,1}; r = g>>2, s = g&3
    const int g0 = tid * 2;
    const int sr0 = g0 >> 2, ss0 = g0 & 3;
    const int sr1 = (g0 + 1) >> 2, ss1 = (g0 + 1) & 3;

    const ushort* pLh = Lhp + (size_t)(row0 + sr0) * O_DIM + ss0 * 8;
    const ushort* pLl = Llp + (size_t)(row0 + sr0) * O_DIM + ss0 * 8;
    const ushort* pMh = Mhp + (size_t)(col0 + sr0) * O_DIM + ss0 * 8;
    const ushort* pMl = Mlp + (size_t)(col0 + sr0) * O_DIM + ss0 * 8;
    const ushort* qLh = Lhp + (size_t)(row0 + sr1) * O_DIM + ss1 * 8;
    const ushort* qLl = Llp + (size_t)(row0 + sr1) * O_DIM + ss1 * 8;
    const ushort* qMh = Mhp + (size_t)(col0 + sr1) * O_DIM + ss1 * 8;
    const ushort* qMl = Mlp + (size_t)(col0 + sr1) * O_DIM + ss1 * 8;

    f32x4 acc[4][4];
#pragma unroll
    for (int i = 0; i < 4; i++)
#pragma unroll
        for (int j = 0; j < 4; j++)
#pragma unroll
            for (int r = 0; r < 4; r++) acc[i][j][r] = 0.0f;

    uint4 vLh0 = *(const uint4*)pLh, vLl0 = *(const uint4*)pLl;
    uint4 vMh0 = *(const uint4*)pMh, vMl0 = *(const uint4*)pMl;
    uint4 vLh1 = *(const uint4*)qLh, vLl1 = *(const uint4*)qLl;
    uint4 vMh1 = *(const uint4*)qMh, vMl1 = *(const uint4*)qMl;

    const int fr = lane & 15;
    const int sl = lane >> 4;

    for (int t = 0; t < O_DIM / 32; t++) {
        __syncthreads();
        *(uint4*)&LhT[TP(sr0, ss0)] = vLh0;  *(uint4*)&LhT[TP(sr1, ss1)] = vLh1;
        *(uint4*)&LlT[TP(sr0, ss0)] = vLl0;  *(uint4*)&LlT[TP(sr1, ss1)] = vLl1;
        *(uint4*)&MhT[TP(sr0, ss0)] = vMh0;  *(uint4*)&MhT[TP(sr1, ss1)] = vMh1;
        *(uint4*)&MlT[TP(sr0, ss0)] = vMl0;  *(uint4*)&MlT[TP(sr1, ss1)] = vMl1;
        __syncthreads();
        if (t + 1 < O_DIM / 32) {
            const int o = (t + 1) * 32;
            vLh0 = *(const uint4*)(pLh + o);  vLl0 = *(const uint4*)(pLl + o);
            vMh0 = *(const uint4*)(pMh + o);  vMl0 = *(const uint4*)(pMl + o);
            vLh1 = *(const uint4*)(qLh + o);  vLl1 = *(const uint4*)(qLl + o);
            vMh1 = *(const uint4*)(qMh + o);  vMl1 = *(const uint4*)(qMl + o);
        }
        f16x8 lh_[4], ll_[4], mh_[4], ml_[4];
#pragma unroll
        for (int mi = 0; mi < 4; mi++) {
            const int r = wm * 64 + mi * 16 + fr;
            lh_[mi] = *(const f16x8*)&LhT[TP(r, sl)];
            ll_[mi] = *(const f16x8*)&LlT[TP(r, sl)];
        }
#pragma unroll
        for (int ni = 0; ni < 4; ni++) {
            const int r = wn * 64 + ni * 16 + fr;
            mh_[ni] = *(const f16x8*)&MhT[TP(r, sl)];
            ml_[ni] = *(const f16x8*)&MlT[TP(r, sl)];
        }
#pragma unroll
        for (int mi = 0; mi < 4; mi++)
#pragma unroll
            for (int ni = 0; ni < 4; ni++) {
                acc[mi][ni] = __builtin_amdgcn_mfma_f32_16x16x32_f16(lh_[mi], mh_[ni], acc[mi][ni], 0, 0, 0);
                acc[mi][ni] = __builtin_amdgcn_mfma_f32_16x16x32_f16(ll_[mi], mh_[ni], acc[mi][ni], 0, 0, 0);
                acc[mi][ni] = __builtin_amdgcn_mfma_f32_16x16x32_f16(lh_[mi], ml_[ni], acc[mi][ni], 0, 0, 0);
            }
    }

    // Epilogue (fast path: u=b=spk=0 -> thr=0.01, u_new = l1*(1+exp(-zm)))
#pragma unroll
    for (int ni = 0; ni < 4; ni++) {
        const int col = col0 + wn * 64 + ni * 16 + fr;
        const float bm = bTm[col];
#pragma unroll
        for (int mi = 0; mi < 4; mi++) {
            const int rb = row0 + wm * 64 + mi * 16 + ((lane >> 4) << 2);
#pragma unroll
            for (int r = 0; r < 4; r++) {
                const size_t idx = (size_t)(rb + r) * O_DIM + col;
                const float zm = acc[mi][ni][r] * WDESCALE + bm;
                const float l1 = h2f(Lhp[idx]) + h2f(Llp[idx]);
                const float ea = expf(-zm);
                const float d = l1 * (1.0f + ea) - 0.01f;
                out[idx] = d > 0.0f ? 1.0f : 0.0f;
                const float tol = 2e-4f + 1e-4f * ea * (1.0f + fabsf(l1));
                if (fabsf(d) < tol) {
                    const uint pos = atomicAdd(cnt, 1u);
                    if (pos < cap) list[pos] = (uint)idx;
                }
            }
        }
    }
}

// ===========================================================================
// Stage-2 SLOW path (general inputs) — round-4 validated kernel, L1 from planes
// ===========================================================================
__global__ __launch_bounds__(512)
void stage2_slow(const ushort* __restrict__ Lhp, const ushort* __restrict__ Llp,
                 const float* __restrict__ u_t, const float* __restrict__ b_t,
                 const float* __restrict__ spk,
                 const float* __restrict__ WTm, const float* __restrict__ bTm,
                 const float* __restrict__ WTa, const float* __restrict__ bTa,
                 float* __restrict__ out, const uint* __restrict__ flag,
                 uint* __restrict__ cnt, uint* __restrict__ list, uint cap) {
    if (*flag == 0) return;

    __shared__ uint A1h[128][20], A1l[128][20], A2h[128][20], A2l[128][20];
    __shared__ uint Mh[128][20],  Ml[128][20],  Gh[128][20],  Gl[128][20];

    const int tid = threadIdx.x;
    const int lane = tid & 63;
    const int wid = tid >> 6;
    const int wm = wid >> 2;
    const int wn = wid & 3;

    int sid = blockIdx.x;
    sid = (sid & 7) * 64 + (sid >> 3);
    const int bx = sid & 15, by = sid >> 4;
    const int row0 = by * 128, col0 = bx * 128;

    const int srow = tid >> 2;
    const int skb = (tid & 3) * 8;
    const int swc = (tid & 3) * 4;

    const size_t aoff = (size_t)(row0 + srow) * O_DIM + skb;
    const float* pU = u_t + aoff;
    const float* pT = b_t + aoff;
    const float* pM = WTm + (size_t)(col0 + srow) * O_DIM + skb;
    const float* pG = WTa + (size_t)(col0 + srow) * O_DIM + skb;

    f32x4 accM[4][2], accA[4][2];
#pragma unroll
    for (int i = 0; i < 4; i++)
#pragma unroll
        for (int j = 0; j < 2; j++)
#pragma unroll
            for (int r = 0; r < 4; r++) { accM[i][j][r] = 0.0f; accA[i][j][r] = 0.0f; }

    float4 lq0, lq1;
    {
        const uint4 LH = *(const uint4*)(Lhp + aoff);
        const uint4 LL = *(const uint4*)(Llp + aoff);
        unpack8(LH, LL, lq0, lq1);
    }
    float4 uq0 = *(const float4*)(pU + 0), uq1 = *(const float4*)(pU + 4);
    float4 tq0 = *(const float4*)(pT + 0), tq1 = *(const float4*)(pT + 4);
    float4 mq0 = *(const float4*)(pM + 0), mq1 = *(const float4*)(pM + 4);
    float4 gq0 = *(const float4*)(pG + 0), gq1 = *(const float4*)(pG + 4);

    const int fr = lane & 15;
    const int kq = (lane >> 4) * 4;

    for (int t = 0; t < O_DIM / 32; t++) {
        uint4 A1hi, A1lo, A2hi, A2lo, Mhi, Mlo, Ghi, Glo;
        split8(add4(lq0, uq0), add4(lq1, uq1), A1hi, A1lo);
        split8(add4(lq0, tq0), add4(lq1, tq1), A2hi, A2lo);
        split8(mul64(mq0), mul64(mq1), Mhi, Mlo);
        split8(mul64(gq0), mul64(gq1), Ghi, Glo);
        __syncthreads();
        *(uint4*)&A1h[srow][swc] = A1hi;  *(uint4*)&A1l[srow][swc] = A1lo;
        *(uint4*)&A2h[srow][swc] = A2hi;  *(uint4*)&A2l[srow][swc] = A2lo;
        *(uint4*)&Mh[srow][swc]  = Mhi;   *(uint4*)&Ml[srow][swc]  = Mlo;
        *(uint4*)&Gh[srow][swc]  = Ghi;   *(uint4*)&Gl[srow][swc]  = Glo;
        __syncthreads();
        if (t + 1 < O_DIM / 32) {
            const int o = (t + 1) * 32;
            const uint4 LH = *(const uint4*)(Lhp + aoff + o);
            const uint4 LL = *(const uint4*)(Llp + aoff + o);
            unpack8(LH, LL, lq0, lq1);
            uq0 = *(const float4*)(pU + o);  uq1 = *(const float4*)(pU + o + 4);
            tq0 = *(const float4*)(pT + o);  tq1 = *(const float4*)(pT + o + 4);
            mq0 = *(const float4*)(pM + o);  mq1 = *(const float4*)(pM + o + 4);
            gq0 = *(const float4*)(pG + o);  gq1 = *(const float4*)(pG + o + 4);
        }
        {
            f16x8 ah_[4], al_[4], bh_[2], bl_[2];
#pragma unroll
            for (int mi = 0; mi < 4; mi++) {
                const int r = wm * 64 + mi * 16 + fr;
                ah_[mi] = *(const f16x8*)&A1h[r][kq];
                al_[mi] = *(const f16x8*)&A1l[r][kq];
            }
#pragma unroll
            for (int ni = 0; ni < 2; ni++) {
                const int r = wn * 32 + ni * 16 + fr;
                bh_[ni] = *(const f16x8*)&Mh[r][kq];
                bl_[ni] = *(const f16x8*)&Ml[r][kq];
            }
#pragma unroll
            for (int mi = 0; mi < 4; mi++)
#pragma unroll
                for (int ni = 0; ni < 2; ni++) {
                    accM[mi][ni] = __builtin_amdgcn_mfma_f32_16x16x32_f16(ah_[mi], bh_[ni], accM[mi][ni], 0, 0, 0);
                    accM[mi][ni] = __builtin_amdgcn_mfma_f32_16x16x32_f16(ah_[mi], bl_[ni], accM[mi][ni], 0, 0, 0);
                    accM[mi][ni] = __builtin_amdgcn_mfma_f32_16x16x32_f16(al_[mi], bh_[ni], accM[mi][ni], 0, 0, 0);
                }
        }
        {
            f16x8 ah_[4], al_[4], bh_[2], bl_[2];
#pragma unroll
            for (int mi = 0; mi < 4; mi++) {
                const int r = wm * 64 + mi * 16 + fr;
                ah_[mi] = *(const f16x8*)&A2h[r][kq];
                al_[mi] = *(const f16x8*)&A2l[r][kq];
            }
#pragma unroll
            for (int ni = 0; ni < 2; ni++) {
                const int r = wn * 32 + ni * 16 + fr;
                bh_[ni] = *(const f16x8*)&Gh[r][kq];
                bl_[ni] = *(const f16x8*)&Gl[r][kq];
            }
#pragma unroll
            for (int mi = 0; mi < 4; mi++)
#pragma unroll
                for (int ni = 0; ni < 2; ni++) {
                    accA[mi][ni] = __builtin_amdgcn_mfma_f32_16x16x32_f16(ah_[mi], bh_[ni], accA[mi][ni], 0, 0, 0);
                    accA[mi][ni] = __builtin_amdgcn_mfma_f32_16x16x32_f16(ah_[mi], bl_[ni], accA[mi][ni], 0, 0, 0);
                    accA[mi][ni] = __builtin_amdgcn_mfma_f32_16x16x32_f16(al_[mi], bh_[ni], accA[mi][ni], 0, 0, 0);
                }
        }
    }

#pragma unroll
    for (int ni = 0; ni < 2; ni++) {
        const int col = col0 + wn * 32 + ni * 16 + fr;
        const float bm = bTm[col], bg = bTa[col];
#pragma unroll
        for (int mi = 0; mi < 4; mi++) {
            const int rb = row0 + wm * 64 + mi * 16 + ((lane >> 4) << 2);
#pragma unroll
            for (int r = 0; r < 4; r++) {
                const size_t idx = (size_t)(rb + r) * O_DIM + col;
                const float zm = accM[mi][ni][r] * WDESCALE + bm;
                const float za = accA[mi][ni][r] * WDESCALE + bg;
                const float ut = u_t[idx], bt = b_t[idx];
                const float sp = spk[idx];
                const float l1 = h2f(Lhp[idx]) + h2f(Llp[idx]);
                const float ea  = expf(-zm);
                const float rho = 1.0f / (1.0f + expf(-za));
                const float bn  = sp + rho * (bt - sp);
                const float thr = 0.01f + 1.8f * bn;
                const float un  = ut + (l1 - ut) * (1.0f + ea);
                const float d   = un - thr;
                out[idx] = d > 0.0f ? 1.0f : 0.0f;
                const float tol = 2e-4f + 1e-4f * ea * (1.0f + fabsf(l1 - ut))
                                + 2e-4f * fabsf(bt - sp);
                if (fabsf(d) < tol) {
                    const uint pos = atomicAdd(cnt, 1u);
                    if (pos < cap) list[pos] = (uint)idx;
                }
            }
        }
    }
}

// ===========================================================================
// Fixup: exact f64 recompute of flagged boundary elements.
// ===========================================================================
__global__ __launch_bounds__(256)
void lsnn_fixup(const ushort* __restrict__ Lhp, const ushort* __restrict__ Llp,
                const float* __restrict__ X, const float* __restrict__ Wsyn,
                const float* __restrict__ bsyn,
                const float* __restrict__ u_t, const float* __restrict__ b_t,
                const float* __restrict__ spk,
                const float* __restrict__ WTm, const float* __restrict__ bTm,
                const float* __restrict__ WTa, const float* __restrict__ bTa,
                const uint* __restrict__ cnt, const uint* __restrict__ list,
                uint cap, float* __restrict__ out) {
    const uint nc = *cnt;
    const uint n = nc < cap ? nc : cap;
    const int lane = threadIdx.x & 63;
    const uint wid = (blockIdx.x * blockDim.x + threadIdx.x) >> 6;
    const uint nw = (gridDim.x * blockDim.x) >> 6;

    for (uint e = wid; e < n; e += nw) {
        const uint idx = list[e];
        const int b = idx >> 11;
        const int o = idx & (O_DIM - 1);

        double l1 = 0.0, zm = 0.0, za = 0.0;
        const float* xr = X + (size_t)b * I_DIM;
        const float* wr = Wsyn + (size_t)o * I_DIM;
        for (int k = lane; k < I_DIM; k += 64)
            l1 = fma((double)xr[k], (double)wr[k], l1);

        const ushort* lhr = Lhp + (size_t)b * O_DIM;
        const ushort* llr = Llp + (size_t)b * O_DIM;
        const float* ur = u_t + (size_t)b * O_DIM;
        const float* tr = b_t + (size_t)b * O_DIM;
        const float* mr = WTm + (size_t)o * O_DIM;
        const float* ar = WTa + (size_t)o * O_DIM;
        for (int k = lane; k < O_DIM; k += 64) {
            const double l = (double)(h2f(lhr[k]) + h2f(llr[k]));
            zm = fma(l + (double)ur[k], (double)mr[k], zm);
            za = fma(l + (double)tr[k], (double)ar[k], za);
        }
#pragma unroll
        for (int off = 32; off > 0; off >>= 1) {
            l1 += __shfl_down(l1, off);
            zm += __shfl_down(zm, off);
            za += __shfl_down(za, off);
        }
        if (lane == 0) {
            l1 += (double)bsyn[o];
            zm += (double)bTm[o];
            za += (double)bTa[o];
            const double inv_alpha = 1.0 + exp(-zm);
            const double rho = 1.0 / (1.0 + exp(-za));
            const double bt = (double)b_t[idx];
            const double sp = (double)spk[idx];
            const double ut = (double)u_t[idx];
            const double b_new = sp + rho * (bt - sp);
            const double thr = 0.01 + 1.8 * b_new;
            const double u_new = ut + (l1 - ut) * inv_alpha;
            out[idx] = (u_new - thr > 0.0) ? 1.0f : 0.0f;
        }
    }
}

// ===========================================================================
extern "C" void kernel_launch(void* const* d_in, const int* in_sizes, int n_in,
                              void* d_out, int out_size, void* d_ws, size_t ws_size,
                              hipStream_t stream) {
    const float* x    = (const float*)d_in[0];
    const float* u_t  = (const float*)d_in[1];
    const float* b_t  = (const float*)d_in[2];
    const float* spk  = (const float*)d_in[3];
    const float* Wsyn = (const float*)d_in[4];
    const float* bsyn = (const float*)d_in[5];
    const float* WTm  = (const float*)d_in[6];
    const float* bTm  = (const float*)d_in[7];
    const float* WTa  = (const float*)d_in[8];
    const float* bTa  = (const float*)d_in[9];
    float* out = (float*)d_out;

    if (ws_size < LIST_OFF + (1u << 16)) return;  // ws observed >= 64 MB

    ushort* Lhp = (ushort*)((char*)d_ws + L1H_OFF);
    ushort* Llp = (ushort*)((char*)d_ws + L1L_OFF);
    ushort* Mhp = (ushort*)((char*)d_ws + MH_OFF);
    ushort* Mlp = (ushort*)((char*)d_ws + ML_OFF);
    uint* flag  = (uint*)((char*)d_ws + FLAG_OFF);
    uint* cnt   = (uint*)((char*)d_ws + CNT_OFF);
    uint* list  = (uint*)((char*)d_ws + LIST_OFF);
    const uint cap = (uint)((ws_size - LIST_OFF) / sizeof(uint));

    (void)hipMemsetAsync((char*)d_ws + FLAG_OFF, 0, 8, stream);
    zcheck<<<dim3(1024), dim3(256), 0, stream>>>(u_t, b_t, spk, flag);
    wsplit<<<dim3(2048), dim3(256), 0, stream>>>(WTm, Mhp, Mlp);
    gemm1_mfma<<<dim3(512), dim3(256), 0, stream>>>(x, Wsyn, bsyn, Lhp, Llp);
    stage2_fast<<<dim3(512), dim3(256), 0, stream>>>(Lhp, Llp, Mhp, Mlp, bTm,
                                                     out, flag, cnt, list, cap);
    stage2_slow<<<dim3(512), dim3(512), 0, stream>>>(Lhp, Llp, u_t, b_t, spk,
                                                     WTm, bTm, WTa, bTa,
                                                     out, flag, cnt, list, cap);
    lsnn_fixup<<<dim3(256), dim3(256), 0, stream>>>(Lhp, Llp, x, Wsyn, bsyn,
                                                    u_t, b_t, spk,
                                                    WTm, bTm, WTa, bTa,
                                                    cnt, list, cap, out);
}

// Round 7
// 297.169 us; speedup vs baseline: 13.5367x; 1.0133x over previous
//
#include <hip/hip_runtime.h>
#include <cmath>

#define B_DIM 4096
#define O_DIM 2048
#define I_DIM 2048

typedef _Float16 f16x8 __attribute__((ext_vector_type(8)));
typedef float f32x4 __attribute__((ext_vector_type(4)));
typedef unsigned int uint;
typedef unsigned short ushort;

#define WSCALE   64.0f
#define WDESCALE 0.015625f

// ws layout
#define L1H_OFF  ((size_t)0)                        // 16 MB
#define L1L_OFF  ((size_t)16 * 1024 * 1024)         // 16 MB
#define MH_OFF   ((size_t)32 * 1024 * 1024)         // 8 MB
#define FLAG_OFF ((size_t)48 * 1024 * 1024)
#define CNT_OFF  (FLAG_OFF + 4)
#define LIST_OFF (FLAG_OFF + 256)

// Swizzled LDS tile: [128 rows][16 dwords]; 16B slot s: phys = s ^ ((r>>1)&3).
__device__ __forceinline__ int TP(int r, int s) {
    return r * 16 + (((s ^ ((r >> 1) & 3))) << 2);
}

__device__ __forceinline__ float h2f(ushort u) {
    _Float16 h = __builtin_bit_cast(_Float16, u);
    return (float)h;
}

// async global->LDS, 16 B per lane; dest = wave-uniform base + lane*16
__device__ __forceinline__ void gload16(const uint* src, uint* lds) {
    __builtin_amdgcn_global_load_lds(
        (const __attribute__((address_space(1))) void*)src,
        (__attribute__((address_space(3))) void*)lds, 16, 0, 0);
}

__device__ __forceinline__ void split8(const float4 a, const float4 b,
                                       uint4& hi, uint4& lo) {
    auto h0 = __builtin_amdgcn_cvt_pkrtz(a.x, a.y);
    auto h1 = __builtin_amdgcn_cvt_pkrtz(a.z, a.w);
    auto h2 = __builtin_amdgcn_cvt_pkrtz(b.x, b.y);
    auto h3 = __builtin_amdgcn_cvt_pkrtz(b.z, b.w);
    auto l0 = __builtin_amdgcn_cvt_pkrtz(a.x - (float)h0[0], a.y - (float)h0[1]);
    auto l1 = __builtin_amdgcn_cvt_pkrtz(a.z - (float)h1[0], a.w - (float)h1[1]);
    auto l2 = __builtin_amdgcn_cvt_pkrtz(b.x - (float)h2[0], b.y - (float)h2[1]);
    auto l3 = __builtin_amdgcn_cvt_pkrtz(b.z - (float)h3[0], b.w - (float)h3[1]);
    hi.x = __builtin_bit_cast(uint, h0); hi.y = __builtin_bit_cast(uint, h1);
    hi.z = __builtin_bit_cast(uint, h2); hi.w = __builtin_bit_cast(uint, h3);
    lo.x = __builtin_bit_cast(uint, l0); lo.y = __builtin_bit_cast(uint, l1);
    lo.z = __builtin_bit_cast(uint, l2); lo.w = __builtin_bit_cast(uint, l3);
}

__device__ __forceinline__ float4 add4(const float4 a, const float4 b) {
    return make_float4(a.x + b.x, a.y + b.y, a.z + b.z, a.w + b.w);
}
__device__ __forceinline__ float4 mul64(const float4 a) {
    return make_float4(a.x * WSCALE, a.y * WSCALE, a.z * WSCALE, a.w * WSCALE);
}
__device__ __forceinline__ void unpack8(const uint4 h, const uint4 l,
                                        float4& f0, float4& f1) {
    f0.x = h2f((ushort)(h.x & 0xffff)) + h2f((ushort)(l.x & 0xffff));
    f0.y = h2f((ushort)(h.x >> 16))    + h2f((ushort)(l.x >> 16));
    f0.z = h2f((ushort)(h.y & 0xffff)) + h2f((ushort)(l.y & 0xffff));
    f0.w = h2f((ushort)(h.y >> 16))    + h2f((ushort)(l.y >> 16));
    f1.x = h2f((ushort)(h.z & 0xffff)) + h2f((ushort)(l.z & 0xffff));
    f1.y = h2f((ushort)(h.z >> 16))    + h2f((ushort)(l.z >> 16));
    f1.z = h2f((ushort)(h.w & 0xffff)) + h2f((ushort)(l.w & 0xffff));
    f1.w = h2f((ushort)(h.w >> 16))    + h2f((ushort)(l.w >> 16));
}

// ===========================================================================
__global__ __launch_bounds__(256)
void zcheck(const float* __restrict__ u, const float* __restrict__ b,
            const float* __restrict__ s, uint* __restrict__ flag) {
    const size_t n4 = (size_t)B_DIM * O_DIM / 4;
    const size_t stride = (size_t)gridDim.x * blockDim.x;
    bool nz = false;
    for (size_t i = blockIdx.x * blockDim.x + threadIdx.x; i < n4; i += stride) {
        const float4 a = ((const float4*)u)[i];
        const float4 c = ((const float4*)b)[i];
        const float4 d = ((const float4*)s)[i];
        nz |= (a.x != 0.f) | (a.y != 0.f) | (a.z != 0.f) | (a.w != 0.f);
        nz |= (c.x != 0.f) | (c.y != 0.f) | (c.z != 0.f) | (c.w != 0.f);
        nz |= (d.x != 0.f) | (d.y != 0.f) | (d.z != 0.f) | (d.w != 0.f);
    }
    if (nz) atomicOr(flag, 1u);
}

// Pre-split WTm*64 -> hi f16 plane only (fast path is single-chain).
__global__ __launch_bounds__(256)
void wsplit(const float* __restrict__ W, ushort* __restrict__ Wh) {
    const size_t i = ((size_t)blockIdx.x * blockDim.x + threadIdx.x) * 8;
    const float4 a = mul64(*(const float4*)(W + i));
    const float4 b = mul64(*(const float4*)(W + i + 4));
    auto h0 = __builtin_amdgcn_cvt_pkrtz(a.x, a.y);
    auto h1 = __builtin_amdgcn_cvt_pkrtz(a.z, a.w);
    auto h2 = __builtin_amdgcn_cvt_pkrtz(b.x, b.y);
    auto h3 = __builtin_amdgcn_cvt_pkrtz(b.z, b.w);
    uint4 h;
    h.x = __builtin_bit_cast(uint, h0); h.y = __builtin_bit_cast(uint, h1);
    h.z = __builtin_bit_cast(uint, h2); h.w = __builtin_bit_cast(uint, h3);
    *(uint4*)(Wh + i) = h;
}

// ===========================================================================
// GEMM1: L1 = X.Wsyn^T + bsyn (3-chain split-f16 MFMA) -> split planes.
// ===========================================================================
__global__ __launch_bounds__(256)
void gemm1_mfma(const float* __restrict__ X, const float* __restrict__ W,
                const float* __restrict__ bias,
                ushort* __restrict__ Lh, ushort* __restrict__ Ll) {
    __shared__ uint Ah[2048], Al[2048], Bh[2048], Bl[2048];

    const int tid = threadIdx.x;
    const int lane = tid & 63;
    const int wid = tid >> 6;
    const int wm = wid >> 1, wn = wid & 1;

    int sid = blockIdx.x;
    sid = (sid & 7) * 64 + (sid >> 3);
    const int bx = sid & 15, by = sid >> 4;
    const int row0 = by * 128, col0 = bx * 128;

    const int sr = tid >> 1;
    const int kh = (tid & 1) * 16;
    const int s0 = (tid & 1) * 2;

    const float* pA = X + (size_t)(row0 + sr) * I_DIM + kh;
    const float* pB = W + (size_t)(col0 + sr) * I_DIM + kh;

    f32x4 acc[4][4];
#pragma unroll
    for (int i = 0; i < 4; i++)
#pragma unroll
        for (int j = 0; j < 4; j++)
#pragma unroll
            for (int r = 0; r < 4; r++) acc[i][j][r] = 0.0f;

    const int fr = lane & 15;
    const int sl = lane >> 4;

    float4 a0 = *(const float4*)(pA + 0), a1 = *(const float4*)(pA + 4);
    float4 a2 = *(const float4*)(pA + 8), a3 = *(const float4*)(pA + 12);
    float4 b0 = *(const float4*)(pB + 0), b1 = *(const float4*)(pB + 4);
    float4 b2 = *(const float4*)(pB + 8), b3 = *(const float4*)(pB + 12);
    uint4 xh0, xl0, xh1, xl1, wh0, wl0, wh1, wl1;
    split8(a0, a1, xh0, xl0);
    split8(a2, a3, xh1, xl1);
    split8(mul64(b0), mul64(b1), wh0, wl0);
    split8(mul64(b2), mul64(b3), wh1, wl1);

    const int NT = I_DIM / 32;
    for (int t = 0; t < NT; t++) {
        __syncthreads();
        *(uint4*)&Ah[TP(sr, s0)] = xh0;  *(uint4*)&Ah[TP(sr, s0 + 1)] = xh1;
        *(uint4*)&Al[TP(sr, s0)] = xl0;  *(uint4*)&Al[TP(sr, s0 + 1)] = xl1;
        *(uint4*)&Bh[TP(sr, s0)] = wh0;  *(uint4*)&Bh[TP(sr, s0 + 1)] = wh1;
        *(uint4*)&Bl[TP(sr, s0)] = wl0;  *(uint4*)&Bl[TP(sr, s0 + 1)] = wl1;
        __syncthreads();
        if (t + 1 < NT) {
            const float* nA = pA + (t + 1) * 32;
            const float* nB = pB + (t + 1) * 32;
            a0 = *(const float4*)(nA + 0); a1 = *(const float4*)(nA + 4);
            a2 = *(const float4*)(nA + 8); a3 = *(const float4*)(nA + 12);
            b0 = *(const float4*)(nB + 0); b1 = *(const float4*)(nB + 4);
            b2 = *(const float4*)(nB + 8); b3 = *(const float4*)(nB + 12);
        }
        f16x8 ah_[4], al_[4], bh_[4], bl_[4];
#pragma unroll
        for (int mi = 0; mi < 4; mi++) {
            const int r = wm * 64 + mi * 16 + fr;
            ah_[mi] = *(const f16x8*)&Ah[TP(r, sl)];
            al_[mi] = *(const f16x8*)&Al[TP(r, sl)];
        }
#pragma unroll
        for (int ni = 0; ni < 4; ni++) {
            const int r = wn * 64 + ni * 16 + fr;
            bh_[ni] = *(const f16x8*)&Bh[TP(r, sl)];
            bl_[ni] = *(const f16x8*)&Bl[TP(r, sl)];
        }
#pragma unroll
        for (int mi = 0; mi < 4; mi++)
#pragma unroll
            for (int ni = 0; ni < 4; ni++) {
                acc[mi][ni] = __builtin_amdgcn_mfma_f32_16x16x32_f16(ah_[mi], bh_[ni], acc[mi][ni], 0, 0, 0);
                acc[mi][ni] = __builtin_amdgcn_mfma_f32_16x16x32_f16(ah_[mi], bl_[ni], acc[mi][ni], 0, 0, 0);
                acc[mi][ni] = __builtin_amdgcn_mfma_f32_16x16x32_f16(al_[mi], bh_[ni], acc[mi][ni], 0, 0, 0);
            }
        if (t + 1 < NT) {
            split8(a0, a1, xh0, xl0);
            split8(a2, a3, xh1, xl1);
            split8(mul64(b0), mul64(b1), wh0, wl0);
            split8(mul64(b2), mul64(b3), wh1, wl1);
        }
    }

#pragma unroll
    for (int ni = 0; ni < 4; ni++) {
        const int col = col0 + wn * 64 + ni * 16 + fr;
        const float bv = bias[col];
#pragma unroll
        for (int mi = 0; mi < 4; mi++) {
            const int rb = row0 + wm * 64 + mi * 16 + ((lane >> 4) << 2);
            float e[4];
#pragma unroll
            for (int r = 0; r < 4; r++) e[r] = acc[mi][ni][r] * WDESCALE + bv;
            auto hp0 = __builtin_amdgcn_cvt_pkrtz(e[0], e[1]);
            auto hp1 = __builtin_amdgcn_cvt_pkrtz(e[2], e[3]);
            auto lp0 = __builtin_amdgcn_cvt_pkrtz(e[0] - (float)hp0[0], e[1] - (float)hp0[1]);
            auto lp1 = __builtin_amdgcn_cvt_pkrtz(e[2] - (float)hp1[0], e[3] - (float)hp1[1]);
            const uint uh0 = __builtin_bit_cast(uint, hp0);
            const uint uh1 = __builtin_bit_cast(uint, hp1);
            const uint ul0 = __builtin_bit_cast(uint, lp0);
            const uint ul1 = __builtin_bit_cast(uint, lp1);
            Lh[(size_t)(rb + 0) * O_DIM + col] = (ushort)(uh0 & 0xffff);
            Lh[(size_t)(rb + 1) * O_DIM + col] = (ushort)(uh0 >> 16);
            Lh[(size_t)(rb + 2) * O_DIM + col] = (ushort)(uh1 & 0xffff);
            Lh[(size_t)(rb + 3) * O_DIM + col] = (ushort)(uh1 >> 16);
            Ll[(size_t)(rb + 0) * O_DIM + col] = (ushort)(ul0 & 0xffff);
            Ll[(size_t)(rb + 1) * O_DIM + col] = (ushort)(ul0 >> 16);
            Ll[(size_t)(rb + 2) * O_DIM + col] = (ushort)(ul1 & 0xffff);
            Ll[(size_t)(rb + 3) * O_DIM + col] = (ushort)(ul1 >> 16);
        }
    }
}

// ===========================================================================
// Stage-2 FAST (u=b=spk=0): zm = L1_hi.Mh^T single-chain f16 MFMA.
// global_load_lds staging; chunk ch covers LDS dwords [ch*256, ch*256+256)
// (64 lanes x 16 B). Pre-swizzled SOURCE addrs; double-buffered.
// ===========================================================================
__global__ __launch_bounds__(256)
void stage2_fast(const ushort* __restrict__ Lhp, const ushort* __restrict__ Llp,
                 const ushort* __restrict__ Mhp,
                 const float* __restrict__ bTm, float* __restrict__ out,
                 const uint* __restrict__ flag,
                 uint* __restrict__ cnt, uint* __restrict__ list, uint cap) {
    if (*flag != 0) return;

    __shared__ uint S[2][4096];   // per buf: [0..2047]=Lh tile, [2048..4095]=Mh tile

    const int tid = threadIdx.x;
    const int lane = tid & 63;
    const int wid = tid >> 6;
    const int wm = wid >> 1, wn = wid & 1;

    int sid = blockIdx.x;
    sid = (sid & 7) * 64 + (sid >> 3);
    const int bx = sid & 15, by = sid >> 4;
    const int row0 = by * 128, col0 = bx * 128;

    // chunk ch = wid*2 + i covers 16B-slots [ch*64, ch*64+64):
    // lane l -> slot g = ch*64+l; r = g>>2; phys slot p = g&3;
    // logical slot q = p ^ ((r>>1)&3); source = row r, slot q.
    const uint* srcL0; const uint* srcL1; const uint* srcM0; const uint* srcM1;
    {
        const int g0 = (wid * 2 + 0) * 64 + lane;
        const int g1 = (wid * 2 + 1) * 64 + lane;
        const int r0 = g0 >> 2, p0 = g0 & 3, q0 = p0 ^ ((r0 >> 1) & 3);
        const int r1 = g1 >> 2, p1 = g1 & 3, q1 = p1 ^ ((r1 >> 1) & 3);
        srcL0 = (const uint*)Lhp + (size_t)(row0 + r0) * (O_DIM / 2) + q0 * 4;
        srcL1 = (const uint*)Lhp + (size_t)(row0 + r1) * (O_DIM / 2) + q1 * 4;
        srcM0 = (const uint*)Mhp + (size_t)(col0 + r0) * (O_DIM / 2) + q0 * 4;
        srcM1 = (const uint*)Mhp + (size_t)(col0 + r1) * (O_DIM / 2) + q1 * 4;
    }
    // FIX (round 6 bug): LDS chunk base is chunk*256 dwords (64 slots x 16 B),
    // not chunk*64 — chunks overlapped and left most of the tile unstaged.
    const int c0 = (wid * 2 + 0) << 8;
    const int c1 = (wid * 2 + 1) << 8;

    f32x4 acc[4][4];
#pragma unroll
    for (int i = 0; i < 4; i++)
#pragma unroll
        for (int j = 0; j < 4; j++)
#pragma unroll
            for (int r = 0; r < 4; r++) acc[i][j][r] = 0.0f;

    const int fr = lane & 15;
    const int sl = lane >> 4;
    const int NT = O_DIM / 32;

    gload16(srcL0, &S[0][c0]);
    gload16(srcL1, &S[0][c1]);
    gload16(srcM0, &S[0][2048 + c0]);
    gload16(srcM1, &S[0][2048 + c1]);
    __syncthreads();

    int buf = 0;
    for (int t = 0; t < NT; t++) {
        if (t + 1 < NT) {
            const int ko = (t + 1) * 16;
            gload16(srcL0 + ko, &S[buf ^ 1][c0]);
            gload16(srcL1 + ko, &S[buf ^ 1][c1]);
            gload16(srcM0 + ko, &S[buf ^ 1][2048 + c0]);
            gload16(srcM1 + ko, &S[buf ^ 1][2048 + c1]);
        }
        f16x8 lh_[4], mh_[4];
#pragma unroll
        for (int mi = 0; mi < 4; mi++)
            lh_[mi] = *(const f16x8*)&S[buf][TP(wm * 64 + mi * 16 + fr, sl)];
#pragma unroll
        for (int ni = 0; ni < 4; ni++)
            mh_[ni] = *(const f16x8*)&S[buf][2048 + TP(wn * 64 + ni * 16 + fr, sl)];
#pragma unroll
        for (int mi = 0; mi < 4; mi++)
#pragma unroll
            for (int ni = 0; ni < 4; ni++)
                acc[mi][ni] = __builtin_amdgcn_mfma_f32_16x16x32_f16(lh_[mi], mh_[ni], acc[mi][ni], 0, 0, 0);
        __syncthreads();   // drains gload_lds (vmcnt) + all reads of buf
        buf ^= 1;
    }

#pragma unroll
    for (int ni = 0; ni < 4; ni++) {
        const int col = col0 + wn * 64 + ni * 16 + fr;
        const float bm = bTm[col];
#pragma unroll
        for (int mi = 0; mi < 4; mi++) {
            const int rb = row0 + wm * 64 + mi * 16 + ((lane >> 4) << 2);
#pragma unroll
            for (int r = 0; r < 4; r++) {
                const size_t idx = (size_t)(rb + r) * O_DIM + col;
                const float zm = acc[mi][ni][r] * WDESCALE + bm;
                const float l1 = h2f(Lhp[idx]) + h2f(Llp[idx]);
                const float ea = expf(-zm);
                const float d = l1 * (1.0f + ea) - 0.01f;
                out[idx] = d > 0.0f ? 1.0f : 0.0f;
                const float tol = 2e-4f + 1e-4f * ea * (1.0f + fabsf(l1));
                if (fabsf(d) < tol) {
                    const uint pos = atomicAdd(cnt, 1u);
                    if (pos < cap) list[pos] = (uint)idx;
                }
            }
        }
    }
}

// ===========================================================================
// Stage-2 SLOW path (general inputs) — round-4 validated structure.
// ===========================================================================
__global__ __launch_bounds__(512)
void stage2_slow(const ushort* __restrict__ Lhp, const ushort* __restrict__ Llp,
                 const float* __restrict__ u_t, const float* __restrict__ b_t,
                 const float* __restrict__ spk,
                 const float* __restrict__ WTm, const float* __restrict__ bTm,
                 const float* __restrict__ WTa, const float* __restrict__ bTa,
                 float* __restrict__ out, const uint* __restrict__ flag,
                 uint* __restrict__ cnt, uint* __restrict__ list, uint cap) {
    if (*flag == 0) return;

    __shared__ uint A1h[128][20], A1l[128][20], A2h[128][20], A2l[128][20];
    __shared__ uint Mh[128][20],  Ml[128][20],  Gh[128][20],  Gl[128][20];

    const int tid = threadIdx.x;
    const int lane = tid & 63;
    const int wid = tid >> 6;
    const int wm = wid >> 2;
    const int wn = wid & 3;

    int sid = blockIdx.x;
    sid = (sid & 7) * 64 + (sid >> 3);
    const int bx = sid & 15, by = sid >> 4;
    const int row0 = by * 128, col0 = bx * 128;

    const int srow = tid >> 2;
    const int skb = (tid & 3) * 8;
    const int swc = (tid & 3) * 4;

    const size_t aoff = (size_t)(row0 + srow) * O_DIM + skb;
    const float* pU = u_t + aoff;
    const float* pT = b_t + aoff;
    const float* pM = WTm + (size_t)(col0 + srow) * O_DIM + skb;
    const float* pG = WTa + (size_t)(col0 + srow) * O_DIM + skb;

    f32x4 accM[4][2], accA[4][2];
#pragma unroll
    for (int i = 0; i < 4; i++)
#pragma unroll
        for (int j = 0; j < 2; j++)
#pragma unroll
            for (int r = 0; r < 4; r++) { accM[i][j][r] = 0.0f; accA[i][j][r] = 0.0f; }

    float4 lq0, lq1;
    {
        const uint4 LH = *(const uint4*)(Lhp + aoff);
        const uint4 LL = *(const uint4*)(Llp + aoff);
        unpack8(LH, LL, lq0, lq1);
    }
    float4 uq0 = *(const float4*)(pU + 0), uq1 = *(const float4*)(pU + 4);
    float4 tq0 = *(const float4*)(pT + 0), tq1 = *(const float4*)(pT + 4);
    float4 mq0 = *(const float4*)(pM + 0), mq1 = *(const float4*)(pM + 4);
    float4 gq0 = *(const float4*)(pG + 0), gq1 = *(const float4*)(pG + 4);

    const int fr = lane & 15;
    const int kq = (lane >> 4) * 4;

    for (int t = 0; t < O_DIM / 32; t++) {
        uint4 A1hi, A1lo, A2hi, A2lo, Mhi, Mlo, Ghi, Glo;
        split8(add4(lq0, uq0), add4(lq1, uq1), A1hi, A1lo);
        split8(add4(lq0, tq0), add4(lq1, tq1), A2hi, A2lo);
        split8(mul64(mq0), mul64(mq1), Mhi, Mlo);
        split8(mul64(gq0), mul64(gq1), Ghi, Glo);
        __syncthreads();
        *(uint4*)&A1h[srow][swc] = A1hi;  *(uint4*)&A1l[srow][swc] = A1lo;
        *(uint4*)&A2h[srow][swc] = A2hi;  *(uint4*)&A2l[srow][swc] = A2lo;
        *(uint4*)&Mh[srow][swc]  = Mhi;   *(uint4*)&Ml[srow][swc]  = Mlo;
        *(uint4*)&Gh[srow][swc]  = Ghi;   *(uint4*)&Gl[srow][swc]  = Glo;
        __syncthreads();
        if (t + 1 < O_DIM / 32) {
            const int o = (t + 1) * 32;
            const uint4 LH = *(const uint4*)(Lhp + aoff + o);
            const uint4 LL = *(const uint4*)(Llp + aoff + o);
            unpack8(LH, LL, lq0, lq1);
            uq0 = *(const float4*)(pU + o);  uq1 = *(const float4*)(pU + o + 4);
            tq0 = *(const float4*)(pT + o);  tq1 = *(const float4*)(pT + o + 4);
            mq0 = *(const float4*)(pM + o);  mq1 = *(const float4*)(pM + o + 4);
            gq0 = *(const float4*)(pG + o);  gq1 = *(const float4*)(pG + o + 4);
        }
        {
            f16x8 ah_[4], al_[4], bh_[2], bl_[2];
#pragma unroll
            for (int mi = 0; mi < 4; mi++) {
                const int r = wm * 64 + mi * 16 + fr;
                ah_[mi] = *(const f16x8*)&A1h[r][kq];
                al_[mi] = *(const f16x8*)&A1l[r][kq];
            }
#pragma unroll
            for (int ni = 0; ni < 2; ni++) {
                const int r = wn * 32 + ni * 16 + fr;
                bh_[ni] = *(const f16x8*)&Mh[r][kq];
                bl_[ni] = *(const f16x8*)&Ml[r][kq];
            }
#pragma unroll
            for (int mi = 0; mi < 4; mi++)
#pragma unroll
                for (int ni = 0; ni < 2; ni++) {
                    accM[mi][ni] = __builtin_amdgcn_mfma_f32_16x16x32_f16(ah_[mi], bh_[ni], accM[mi][ni], 0, 0, 0);
                    accM[mi][ni] = __builtin_amdgcn_mfma_f32_16x16x32_f16(ah_[mi], bl_[ni], accM[mi][ni], 0, 0, 0);
                    accM[mi][ni] = __builtin_amdgcn_mfma_f32_16x16x32_f16(al_[mi], bh_[ni], accM[mi][ni], 0, 0, 0);
                }
        }
        {
            f16x8 ah_[4], al_[4], bh_[2], bl_[2];
#pragma unroll
            for (int mi = 0; mi < 4; mi++) {
                const int r = wm * 64 + mi * 16 + fr;
                ah_[mi] = *(const f16x8*)&A2h[r][kq];
                al_[mi] = *(const f16x8*)&A2l[r][kq];
            }
#pragma unroll
            for (int ni = 0; ni < 2; ni++) {
                const int r = wn * 32 + ni * 16 + fr;
                bh_[ni] = *(const f16x8*)&Gh[r][kq];
                bl_[ni] = *(const f16x8*)&Gl[r][kq];
            }
#pragma unroll
            for (int mi = 0; mi < 4; mi++)
#pragma unroll
                for (int ni = 0; ni < 2; ni++) {
                    accA[mi][ni] = __builtin_amdgcn_mfma_f32_16x16x32_f16(ah_[mi], bh_[ni], accA[mi][ni], 0, 0, 0);
                    accA[mi][ni] = __builtin_amdgcn_mfma_f32_16x16x32_f16(ah_[mi], bl_[ni], accA[mi][ni], 0, 0, 0);
                    accA[mi][ni] = __builtin_amdgcn_mfma_f32_16x16x32_f16(al_[mi], bh_[ni], accA[mi][ni], 0, 0, 0);
                }
        }
    }

#pragma unroll
    for (int ni = 0; ni < 2; ni++) {
        const int col = col0 + wn * 32 + ni * 16 + fr;
        const float bm = bTm[col], bg = bTa[col];
#pragma unroll
        for (int mi = 0; mi < 4; mi++) {
            const int rb = row0 + wm * 64 + mi * 16 + ((lane >> 4) << 2);
#pragma unroll
            for (int r = 0; r < 4; r++) {
                const size_t idx = (size_t)(rb + r) * O_DIM + col;
                const float zm = accM[mi][ni][r] * WDESCALE + bm;
                const float za = accA[mi][ni][r] * WDESCALE + bg;
                const float ut = u_t[idx], bt = b_t[idx];
                const float sp = spk[idx];
                const float l1 = h2f(Lhp[idx]) + h2f(Llp[idx]);
                const float ea  = expf(-zm);
                const float rho = 1.0f / (1.0f + expf(-za));
                const float bn  = sp + rho * (bt - sp);
                const float thr = 0.01f + 1.8f * bn;
                const float un  = ut + (l1 - ut) * (1.0f + ea);
                const float d   = un - thr;
                out[idx] = d > 0.0f ? 1.0f : 0.0f;
                const float tol = 2e-4f + 1e-4f * ea * (1.0f + fabsf(l1 - ut))
                                + 2e-4f * fabsf(bt - sp);
                if (fabsf(d) < tol) {
                    const uint pos = atomicAdd(cnt, 1u);
                    if (pos < cap) list[pos] = (uint)idx;
                }
            }
        }
    }
}

// ===========================================================================
__global__ __launch_bounds__(256)
void lsnn_fixup(const ushort* __restrict__ Lhp, const ushort* __restrict__ Llp,
                const float* __restrict__ X, const float* __restrict__ Wsyn,
                const float* __restrict__ bsyn,
                const float* __restrict__ u_t, const float* __restrict__ b_t,
                const float* __restrict__ spk,
                const float* __restrict__ WTm, const float* __restrict__ bTm,
                const float* __restrict__ WTa, const float* __restrict__ bTa,
                const uint* __restrict__ cnt, const uint* __restrict__ list,
                uint cap, float* __restrict__ out) {
    const uint nc = *cnt;
    const uint n = nc < cap ? nc : cap;
    const int lane = threadIdx.x & 63;
    const uint wid = (blockIdx.x * blockDim.x + threadIdx.x) >> 6;
    const uint nw = (gridDim.x * blockDim.x) >> 6;

    for (uint e = wid; e < n; e += nw) {
        const uint idx = list[e];
        const int b = idx >> 11;
        const int o = idx & (O_DIM - 1);

        double l1 = 0.0, zm = 0.0, za = 0.0;
        const float* xr = X + (size_t)b * I_DIM;
        const float* wr = Wsyn + (size_t)o * I_DIM;
        for (int k = lane; k < I_DIM; k += 64)
            l1 = fma((double)xr[k], (double)wr[k], l1);

        const ushort* lhr = Lhp + (size_t)b * O_DIM;
        const ushort* llr = Llp + (size_t)b * O_DIM;
        const float* ur = u_t + (size_t)b * O_DIM;
        const float* tr = b_t + (size_t)b * O_DIM;
        const float* mr = WTm + (size_t)o * O_DIM;
        const float* ar = WTa + (size_t)o * O_DIM;
        for (int k = lane; k < O_DIM; k += 64) {
            const double l = (double)(h2f(lhr[k]) + h2f(llr[k]));
            zm = fma(l + (double)ur[k], (double)mr[k], zm);
            za = fma(l + (double)tr[k], (double)ar[k], za);
        }
#pragma unroll
        for (int off = 32; off > 0; off >>= 1) {
            l1 += __shfl_down(l1, off);
            zm += __shfl_down(zm, off);
            za += __shfl_down(za, off);
        }
        if (lane == 0) {
            l1 += (double)bsyn[o];
            zm += (double)bTm[o];
            za += (double)bTa[o];
            const double inv_alpha = 1.0 + exp(-zm);
            const double rho = 1.0 / (1.0 + exp(-za));
            const double bt = (double)b_t[idx];
            const double sp = (double)spk[idx];
            const double ut = (double)u_t[idx];
            const double b_new = sp + rho * (bt - sp);
            const double thr = 0.01 + 1.8 * b_new;
            const double u_new = ut + (l1 - ut) * inv_alpha;
            out[idx] = (u_new - thr > 0.0) ? 1.0f : 0.0f;
        }
    }
}

// ===========================================================================
extern "C" void kernel_launch(void* const* d_in, const int* in_sizes, int n_in,
                              void* d_out, int out_size, void* d_ws, size_t ws_size,
                              hipStream_t stream) {
    const float* x    = (const float*)d_in[0];
    const float* u_t  = (const float*)d_in[1];
    const float* b_t  = (const float*)d_in[2];
    const float* spk  = (const float*)d_in[3];
    const float* Wsyn = (const float*)d_in[4];
    const float* bsyn = (const float*)d_in[5];
    const float* WTm  = (const float*)d_in[6];
    const float* bTm  = (const float*)d_in[7];
    const float* WTa  = (const float*)d_in[8];
    const float* bTa  = (const float*)d_in[9];
    float* out = (float*)d_out;

    if (ws_size < LIST_OFF + (1u << 16)) return;

    ushort* Lhp = (ushort*)((char*)d_ws + L1H_OFF);
    ushort* Llp = (ushort*)((char*)d_ws + L1L_OFF);
    ushort* Mhp = (ushort*)((char*)d_ws + MH_OFF);
    uint* flag  = (uint*)((char*)d_ws + FLAG_OFF);
    uint* cnt   = (uint*)((char*)d_ws + CNT_OFF);
    uint* list  = (uint*)((char*)d_ws + LIST_OFF);
    const uint cap = (uint)((ws_size - LIST_OFF) / sizeof(uint));

    (void)hipMemsetAsync((char*)d_ws + FLAG_OFF, 0, 8, stream);
    zcheck<<<dim3(1024), dim3(256), 0, stream>>>(u_t, b_t, spk, flag);
    wsplit<<<dim3(2048), dim3(256), 0, stream>>>(WTm, Mhp);
    gemm1_mfma<<<dim3(512), dim3(256), 0, stream>>>(x, Wsyn, bsyn, Lhp, Llp);
    stage2_fast<<<dim3(512), dim3(256), 0, stream>>>(Lhp, Llp, Mhp, bTm,
                                                     out, flag, cnt, list, cap);
    stage2_slow<<<dim3(512), dim3(512), 0, stream>>>(Lhp, Llp, u_t, b_t, spk,
                                                     WTm, bTm, WTa, bTa,
                                                     out, flag, cnt, list, cap);
    lsnn_fixup<<<dim3(256), dim3(256), 0, stream>>>(Lhp, Llp, x, Wsyn, bsyn,
                                                    u_t, b_t, spk,
                                                    WTm, bTm, WTa, bTa,
                                                    cnt, list, cap, out);
}